// Round 1
// baseline (978.549 us; speedup 1.0000x reference)
//
#include <hip/hip_runtime.h>
#include <stdint.h>

typedef unsigned short u16;
typedef unsigned int u32;

#define T_SEQ 1024
#define HID   2048
#define NH    32
#define HD    64
#define NCHUNK 16
#define INTER 5632

typedef __attribute__((ext_vector_type(8))) short b16x8;
typedef __attribute__((ext_vector_type(4))) float f32x4;

__device__ inline float bf2f(u16 u) { union { u32 i; float f; } v; v.i = ((u32)u) << 16; return v.f; }
__device__ inline u16 f2bf(float f) {
  union { float f; u32 i; } v; v.f = f;
  u32 u = v.i;
  return (u16)((u + 0x7FFFu + ((u >> 16) & 1u)) >> 16);  // RNE
}
__device__ inline float silu_f(float x) { return x / (1.f + __expf(-x)); }

// ---------------- fp32 -> bf16 weight conversion ----------------
__global__ __launch_bounds__(256) void k_cvt(const float* __restrict__ s, u16* __restrict__ d, int n4) {
  int i = blockIdx.x * 256 + threadIdx.x;
  if (i < n4) {
    float4 v = ((const float4*)s)[i];
    u32 lo = (u32)f2bf(v.x) | ((u32)f2bf(v.y) << 16);
    u32 hi = (u32)f2bf(v.z) | ((u32)f2bf(v.w) << 16);
    ((uint2*)d)[i] = make_uint2(lo, hi);
  }
}

// ---------------- RMSNorm: fp32 in -> bf16 out ----------------
__global__ __launch_bounds__(256) void k_rms(const float* __restrict__ x, const float* __restrict__ w,
                                             u16* __restrict__ out) {
  int row = blockIdx.x, tid = threadIdx.x;
  const float* xr = x + (size_t)row * HID;
  float4 v0 = ((const float4*)xr)[tid];
  float4 v1 = ((const float4*)xr)[tid + 256];
  float ss = v0.x * v0.x + v0.y * v0.y + v0.z * v0.z + v0.w * v0.w +
             v1.x * v1.x + v1.y * v1.y + v1.z * v1.z + v1.w * v1.w;
  for (int m = 32; m; m >>= 1) ss += __shfl_xor(ss, m, 64);
  __shared__ float wsum[4];
  if ((tid & 63) == 0) wsum[tid >> 6] = ss;
  __syncthreads();
  float tot = wsum[0] + wsum[1] + wsum[2] + wsum[3];
  float sc = rsqrtf(tot / (float)HID + 1e-6f);
  float4 w0 = ((const float4*)w)[tid];
  float4 w1 = ((const float4*)w)[tid + 256];
  u32 lo, hi;
  lo = (u32)f2bf(v0.x * sc * w0.x) | ((u32)f2bf(v0.y * sc * w0.y) << 16);
  hi = (u32)f2bf(v0.z * sc * w0.z) | ((u32)f2bf(v0.w * sc * w0.w) << 16);
  ((uint2*)out)[(size_t)row * 512 + tid] = make_uint2(lo, hi);
  lo = (u32)f2bf(v1.x * sc * w1.x) | ((u32)f2bf(v1.y * sc * w1.y) << 16);
  hi = (u32)f2bf(v1.z * sc * w1.z) | ((u32)f2bf(v1.w * sc * w1.w) << 16);
  ((uint2*)out)[(size_t)row * 512 + tid + 256] = make_uint2(lo, hi);
}

// ---------------- bf16 GEMM: C[M,N] = A[M,K] @ B[N,K]^T (+resid), fp32 out ----------------
// 128x128 tile, BK=32, 256 thr = 4 waves (2x2), each wave 64x64 via 4x4 of 16x16x32 mfma.
__global__ __launch_bounds__(256) void k_gemm(
    const u16* __restrict__ A,
    const u16* __restrict__ B0, const u16* __restrict__ B1, const u16* __restrict__ B2,
    float* __restrict__ C0, float* __restrict__ C1, float* __restrict__ C2,
    const float* __restrict__ resid, int M, int N, int K) {
  const u16* Bp = (blockIdx.z == 0) ? B0 : (blockIdx.z == 1 ? B1 : B2);
  float* Cp = (blockIdx.z == 0) ? C0 : (blockIdx.z == 1 ? C1 : C2);
  __shared__ __align__(16) u16 As[128 * 32];
  __shared__ __align__(16) u16 Bs[128 * 32];
  int tid = threadIdx.x;
  int m0 = blockIdx.y * 128, n0 = blockIdx.x * 128;
  int lane = tid & 63, wv = tid >> 6, wr = wv >> 1, wc = wv & 1;
  int lrow = lane & 15, quad = lane >> 4;
  f32x4 acc[4][4];
#pragma unroll
  for (int i = 0; i < 4; ++i)
#pragma unroll
    for (int j = 0; j < 4; ++j) acc[i][j] = (f32x4){0.f, 0.f, 0.f, 0.f};

  for (int k0 = 0; k0 < K; k0 += 32) {
#pragma unroll
    for (int i = 0; i < 2; ++i) {
      int t = i * 256 + tid;
      int row = t >> 2, col = (t & 3) * 8;
      *(uint4*)&As[row * 32 + col] = *(const uint4*)&A[(size_t)(m0 + row) * K + k0 + col];
      *(uint4*)&Bs[row * 32 + col] = *(const uint4*)&Bp[(size_t)(n0 + row) * K + k0 + col];
    }
    __syncthreads();
    b16x8 af[4], bfr[4];
#pragma unroll
    for (int i = 0; i < 4; ++i) af[i] = *(const b16x8*)&As[(wr * 64 + i * 16 + lrow) * 32 + quad * 8];
#pragma unroll
    for (int j = 0; j < 4; ++j) bfr[j] = *(const b16x8*)&Bs[(wc * 64 + j * 16 + lrow) * 32 + quad * 8];
#pragma unroll
    for (int i = 0; i < 4; ++i)
#pragma unroll
      for (int j = 0; j < 4; ++j)
        acc[i][j] = __builtin_amdgcn_mfma_f32_16x16x32_bf16(af[i], bfr[j], acc[i][j], 0, 0, 0);
    __syncthreads();
  }
#pragma unroll
  for (int i = 0; i < 4; ++i)
#pragma unroll
    for (int j = 0; j < 4; ++j)
#pragma unroll
      for (int r = 0; r < 4; ++r) {
        int row = m0 + wr * 64 + i * 16 + quad * 4 + r;
        int col = n0 + wc * 64 + j * 16 + lrow;
        float val = acc[i][j][r];
        if (resid) val += resid[(size_t)row * N + col];
        Cp[(size_t)row * N + col] = val;
      }
}

// ---------------- beta = sigmoid(h @ Wbeta^T), h bf16, Wbeta fp32 ----------------
__global__ __launch_bounds__(256) void k_beta(const u16* __restrict__ hbf, const float* __restrict__ Wb,
                                              float* __restrict__ beta) {
  __shared__ __align__(16) float hr[HID];
  __shared__ float red[256];
  int t = blockIdx.x, tid = threadIdx.x;
#pragma unroll
  for (int i = 0; i < 8; ++i) {
    int c = i * 256 + tid;
    hr[c] = bf2f(hbf[(size_t)t * HID + c]);
  }
  __syncthreads();
  int head = tid >> 3, j = tid & 7;
  const float* wrow = Wb + (size_t)head * HID + j * 256;
  const float* hs = hr + j * 256;
  float acc = 0.f;
#pragma unroll 16
  for (int c = 0; c < 256; c += 4) {
    float4 wv = *(const float4*)&wrow[c];
    float4 hv = *(const float4*)&hs[c];
    acc += hv.x * wv.x + hv.y * wv.y + hv.z * wv.z + hv.w * wv.w;
  }
  red[tid] = acc;
  __syncthreads();
  if (tid < 32) {
    float s = 0.f;
#pragma unroll
    for (int i = 0; i < 8; ++i) s += red[tid * 8 + i];
    beta[(size_t)t * NH + tid] = 1.f / (1.f + __expf(-s));
  }
}

// ---------------- causal depthwise conv (K=4) + silu(silu) (+ per-head l2norm for q,k) ----------------
__global__ __launch_bounds__(256) void k_conv(const float* __restrict__ proj,
                                              const float* __restrict__ cw0, const float* __restrict__ cw1,
                                              const float* __restrict__ cw2, float* __restrict__ outp) {
  int z = blockIdx.z;
  const float* src = proj + (size_t)z * T_SEQ * HID;
  float* dst = outp + (size_t)z * T_SEQ * HID;
  const float* cw = (z == 0) ? cw0 : (z == 1 ? cw1 : cw2);
  bool l2 = (z < 2);
  int c = threadIdx.x & 63, wr = threadIdx.x >> 6;
  int head = blockIdx.y;
  int ch = head * 64 + c;
  int t0 = blockIdx.x * 64 + wr * 16;
  float4 w = ((const float4*)cw)[ch];
  float xm3 = (t0 >= 3) ? src[(size_t)(t0 - 3) * HID + ch] : 0.f;
  float xm2 = (t0 >= 2) ? src[(size_t)(t0 - 2) * HID + ch] : 0.f;
  float xm1 = (t0 >= 1) ? src[(size_t)(t0 - 1) * HID + ch] : 0.f;
  for (int i = 0; i < 16; ++i) {
    int t = t0 + i;
    float x0 = src[(size_t)t * HID + ch];
    float zv = xm3 * w.x + xm2 * w.y + xm1 * w.z + x0 * w.w;
    float s = silu_f(silu_f(zv));
    if (l2) {
      float ss = s * s;
      for (int m = 32; m; m >>= 1) ss += __shfl_xor(ss, m, 64);
      float n = sqrtf(ss);
      s = s / fmaxf(n, 1e-12f);
    }
    dst[(size_t)t * HID + ch] = s;
    xm3 = xm2; xm2 = xm1; xm1 = x0;
  }
}

// ---------------- Delta scan phase A: per (chunk, head): A=tril(beta*K K^T,-1), P=tril(Q K^T),
//                  forward-subst solves W=(I+A)^-1(beta*K), Uv=(I+A)^-1(beta*V) ----------------
__global__ __launch_bounds__(256) void k_phaseA(
    const float* __restrict__ qp, const float* __restrict__ kp, const float* __restrict__ vp,
    const float* __restrict__ beta, float* __restrict__ Wws, float* __restrict__ Uvws,
    float* __restrict__ Pws) {
  int cx = blockIdx.x, h = blockIdx.y;
  __shared__ __align__(16) u16 Kst[64 * 72];
  __shared__ __align__(16) u16 Qst[64 * 72];
  __shared__ __align__(16) float Af[64 * 68];
  __shared__ float bet[64];
  int tid = threadIdx.x;
  int t0 = cx * 64;
#pragma unroll
  for (int i = 0; i < 16; ++i) {
    int idx = i * 256 + tid, s = idx >> 6, d = idx & 63;
    size_t g = (size_t)(t0 + s) * HID + h * 64 + d;
    Kst[s * 72 + d] = f2bf(kp[g]);
    Qst[s * 72 + d] = f2bf(qp[g]);
  }
  if (tid < 64) bet[tid] = beta[(size_t)(t0 + tid) * NH + h];
  __syncthreads();
  int lane = tid & 63, wv = tid >> 6, lrow = lane & 15, quad = lane >> 4;
  f32x4 accA[4], accP[4];
#pragma unroll
  for (int i = 0; i < 4; ++i) { accA[i] = (f32x4){0.f, 0.f, 0.f, 0.f}; accP[i] = (f32x4){0.f, 0.f, 0.f, 0.f}; }
#pragma unroll
  for (int ks = 0; ks < 2; ++ks) {
    b16x8 bk = *(const b16x8*)&Kst[(wv * 16 + lrow) * 72 + ks * 32 + quad * 8];
#pragma unroll
    for (int i = 0; i < 4; ++i) {
      b16x8 ak = *(const b16x8*)&Kst[(i * 16 + lrow) * 72 + ks * 32 + quad * 8];
      b16x8 aq = *(const b16x8*)&Qst[(i * 16 + lrow) * 72 + ks * 32 + quad * 8];
      accA[i] = __builtin_amdgcn_mfma_f32_16x16x32_bf16(ak, bk, accA[i], 0, 0, 0);
      accP[i] = __builtin_amdgcn_mfma_f32_16x16x32_bf16(aq, bk, accP[i], 0, 0, 0);
    }
  }
  size_t cb = ((size_t)h * NCHUNK + cx) * 4096;
#pragma unroll
  for (int i = 0; i < 4; ++i)
#pragma unroll
    for (int r = 0; r < 4; ++r) {
      int srow = i * 16 + quad * 4 + r, col = wv * 16 + lrow;
      Af[srow * 68 + col] = (col < srow) ? accA[i][r] * bet[srow] : 0.f;
      Pws[cb + srow * 64 + col] = (col <= srow) ? accP[i][r] : 0.f;
    }
  __syncthreads();
  if (wv < 2) {
    int c = lane;
    float x[64];
    if (wv == 0) {
#pragma unroll
      for (int s = 0; s < 64; ++s) x[s] = bet[s] * bf2f(Kst[s * 72 + c]);
    } else {
#pragma unroll
      for (int s = 0; s < 64; ++s) x[s] = bet[s] * vp[(size_t)(t0 + s) * HID + h * 64 + c];
    }
#pragma unroll
    for (int s = 1; s < 64; ++s) {
      float a = 0.f;
#pragma unroll
      for (int r = 0; r < (s & ~3); r += 4) {
        float4 av = *(const float4*)&Af[s * 68 + r];
        a += av.x * x[r] + av.y * x[r + 1] + av.z * x[r + 2] + av.w * x[r + 3];
      }
#pragma unroll
      for (int r = (s & ~3); r < s; ++r) a += Af[s * 68 + r] * x[r];
      x[s] -= a;
    }
    float* dst = ((wv == 0) ? Wws : Uvws) + cb;
#pragma unroll
    for (int s = 0; s < 64; ++s) dst[s * 64 + c] = x[s];
  }
}

// ---------------- Delta scan phase B: sequential over chunks per head.
// U = Uv - W S0^T ; O = Q S0^T + P U ; S1 = S0 + U^T K ----------------
__global__ __launch_bounds__(256) void k_phaseB(
    const float* __restrict__ qp, const float* __restrict__ kp,
    const float* __restrict__ Wws, const float* __restrict__ Uvws, const float* __restrict__ Pws,
    float* __restrict__ o, float* __restrict__ Sout) {
  int h = blockIdx.x, tid = threadIdx.x;
  __shared__ __align__(16) float S0f[64 * 68];
  __shared__ __align__(16) u16 S0b[64 * 72];
  __shared__ __align__(16) u16 Ut[64 * 72];
  __shared__ __align__(16) u16 stA[64 * 72];  // -W, later Q
  __shared__ __align__(16) u16 stP[64 * 72];
  __shared__ __align__(16) u16 stK[64 * 72];  // K transposed: stK[d][s]
  int lane = tid & 63, wv = tid >> 6, lrow = lane & 15, quad = lane >> 4;
#pragma unroll
  for (int i = 0; i < 16; ++i) {
    int idx = i * 256 + tid;
    S0f[(idx >> 6) * 68 + (idx & 63)] = 0.f;
    S0b[(idx >> 6) * 72 + (idx & 63)] = 0;
  }
  __syncthreads();
  for (int cx = 0; cx < NCHUNK; ++cx) {
    size_t cb = ((size_t)h * NCHUNK + cx) * 4096;
    int t0 = cx * 64;
#pragma unroll
    for (int i = 0; i < 16; ++i) {
      int idx = i * 256 + tid, s = idx >> 6, d = idx & 63;
      stA[s * 72 + d] = f2bf(-Wws[cb + idx]);
      stP[s * 72 + d] = f2bf(Pws[cb + idx]);
      stK[d * 72 + s] = f2bf(kp[(size_t)(t0 + s) * HID + h * 64 + d]);
    }
    __syncthreads();
    // --- U = Uv + (-W) S0^T ---
    f32x4 aU[4];
#pragma unroll
    for (int i = 0; i < 4; ++i)
#pragma unroll
      for (int r = 0; r < 4; ++r)
        aU[i][r] = Uvws[cb + (i * 16 + quad * 4 + r) * 64 + wv * 16 + lrow];
#pragma unroll
    for (int ks = 0; ks < 2; ++ks) {
      b16x8 bS = *(const b16x8*)&S0b[(wv * 16 + lrow) * 72 + ks * 32 + quad * 8];
#pragma unroll
      for (int i = 0; i < 4; ++i) {
        b16x8 a = *(const b16x8*)&stA[(i * 16 + lrow) * 72 + ks * 32 + quad * 8];
        aU[i] = __builtin_amdgcn_mfma_f32_16x16x32_bf16(a, bS, aU[i], 0, 0, 0);
      }
    }
#pragma unroll
    for (int i = 0; i < 4; ++i)
#pragma unroll
      for (int r = 0; r < 4; ++r) {
        int s = i * 16 + quad * 4 + r;
        Ut[(wv * 16 + lrow) * 72 + s] = f2bf(aU[i][r]);
      }
    __syncthreads();
    // stage Q into stA
#pragma unroll
    for (int i = 0; i < 16; ++i) {
      int idx = i * 256 + tid, s = idx >> 6, d = idx & 63;
      stA[s * 72 + d] = f2bf(qp[(size_t)(t0 + s) * HID + h * 64 + d]);
    }
    __syncthreads();
    // --- O = Q S0^T + P U ---
    f32x4 aO[4];
#pragma unroll
    for (int i = 0; i < 4; ++i) aO[i] = (f32x4){0.f, 0.f, 0.f, 0.f};
#pragma unroll
    for (int ks = 0; ks < 2; ++ks) {
      b16x8 bS = *(const b16x8*)&S0b[(wv * 16 + lrow) * 72 + ks * 32 + quad * 8];
#pragma unroll
      for (int i = 0; i < 4; ++i) {
        b16x8 a = *(const b16x8*)&stA[(i * 16 + lrow) * 72 + ks * 32 + quad * 8];
        aO[i] = __builtin_amdgcn_mfma_f32_16x16x32_bf16(a, bS, aO[i], 0, 0, 0);
      }
    }
#pragma unroll
    for (int ks = 0; ks < 2; ++ks) {
      b16x8 bU = *(const b16x8*)&Ut[(wv * 16 + lrow) * 72 + ks * 32 + quad * 8];
#pragma unroll
      for (int i = 0; i < 4; ++i) {
        b16x8 a = *(const b16x8*)&stP[(i * 16 + lrow) * 72 + ks * 32 + quad * 8];
        aO[i] = __builtin_amdgcn_mfma_f32_16x16x32_bf16(a, bU, aO[i], 0, 0, 0);
      }
    }
#pragma unroll
    for (int i = 0; i < 4; ++i)
#pragma unroll
      for (int r = 0; r < 4; ++r) {
        int t = i * 16 + quad * 4 + r;
        o[(size_t)(t0 + t) * HID + h * 64 + wv * 16 + lrow] = aO[i][r];
      }
    // --- S1 = S0 + U^T K ---
    f32x4 aS[4];
#pragma unroll
    for (int i = 0; i < 4; ++i)
#pragma unroll
      for (int r = 0; r < 4; ++r)
        aS[i][r] = S0f[(i * 16 + quad * 4 + r) * 68 + wv * 16 + lrow];
#pragma unroll
    for (int ks = 0; ks < 2; ++ks) {
      b16x8 bK = *(const b16x8*)&stK[(wv * 16 + lrow) * 72 + ks * 32 + quad * 8];
#pragma unroll
      for (int i = 0; i < 4; ++i) {
        b16x8 a = *(const b16x8*)&Ut[(i * 16 + lrow) * 72 + ks * 32 + quad * 8];
        aS[i] = __builtin_amdgcn_mfma_f32_16x16x32_bf16(a, bK, aS[i], 0, 0, 0);
      }
    }
    __syncthreads();
#pragma unroll
    for (int i = 0; i < 4; ++i)
#pragma unroll
      for (int r = 0; r < 4; ++r) {
        int vvr = i * 16 + quad * 4 + r, kd = wv * 16 + lrow;
        S0f[vvr * 68 + kd] = aS[i][r];
        S0b[vvr * 72 + kd] = f2bf(aS[i][r]);
      }
    __syncthreads();
  }
#pragma unroll
  for (int i = 0; i < 16; ++i) {
    int idx = i * 256 + tid;
    Sout[(size_t)h * 4096 + idx] = S0f[(idx >> 6) * 68 + (idx & 63)];
  }
}

// ---------------- swiglu: g_bf = bf16(silu(gate)*up) ----------------
__global__ __launch_bounds__(256) void k_swiglu(const float* __restrict__ g, const float* __restrict__ u,
                                                u16* __restrict__ d) {
  int i = blockIdx.x * 256 + threadIdx.x;
  float4 gv = ((const float4*)g)[i];
  float4 uv = ((const float4*)u)[i];
  u32 lo = (u32)f2bf(silu_f(gv.x) * uv.x) | ((u32)f2bf(silu_f(gv.y) * uv.y) << 16);
  u32 hi = (u32)f2bf(silu_f(gv.z) * uv.z) | ((u32)f2bf(silu_f(gv.w) * uv.w) << 16);
  ((uint2*)d)[i] = make_uint2(lo, hi);
}

extern "C" void kernel_launch(void* const* d_in, const int* in_sizes, int n_in,
                              void* d_out, int out_size, void* d_ws, size_t ws_size,
                              hipStream_t stream) {
  const float* x     = (const float*)d_in[0];
  const float* anw   = (const float*)d_in[1];
  const float* Wq    = (const float*)d_in[2];
  const float* Wk    = (const float*)d_in[3];
  const float* Wv    = (const float*)d_in[4];
  const float* convq = (const float*)d_in[5];
  const float* convk = (const float*)d_in[6];
  const float* convv = (const float*)d_in[7];
  const float* Wbeta = (const float*)d_in[8];
  const float* onw   = (const float*)d_in[9];
  const float* Wout  = (const float*)d_in[10];
  const float* mnw   = (const float*)d_in[11];
  const float* Wgate = (const float*)d_in[12];
  const float* Wup   = (const float*)d_in[13];
  const float* Wdown = (const float*)d_in[14];
  float* out = (float*)d_out;

  const size_t TH = (size_t)T_SEQ * HID;        // 2097152
  char* wsb = (char*)d_ws;
  size_t off = 0;
  auto alloc = [&](size_t bytes) -> void* {
    void* p = wsb + off;
    off += (bytes + 255) & ~(size_t)255;
    return p;
  };
  u16* wq_bf   = (u16*)alloc((size_t)HID * HID * 2);
  u16* wk_bf   = (u16*)alloc((size_t)HID * HID * 2);
  u16* wv_bf   = (u16*)alloc((size_t)HID * HID * 2);
  u16* wout_bf = (u16*)alloc((size_t)HID * HID * 2);
  u16* wgate_bf = (u16*)alloc((size_t)INTER * HID * 2);
  u16* wup_bf   = (u16*)alloc((size_t)INTER * HID * 2);
  u16* wdown_bf = (u16*)alloc((size_t)HID * INTER * 2);
  u16* actbf    = (u16*)alloc(TH * 2);                 // h_bf -> onorm_bf -> h2_bf (sequential reuse)
  float* qkv_proj = (float*)alloc(3 * TH * 4);         // later aliased by 'gate'
  float* qkvpost  = (float*)alloc(3 * TH * 4);         // later aliased by 'up'
  float* betab    = (float*)alloc((size_t)T_SEQ * NH * 4);
  float* Wws  = (float*)alloc((size_t)NH * NCHUNK * 4096 * 4);  // later aliased by g_bf
  float* Uvws = (float*)alloc((size_t)NH * NCHUNK * 4096 * 4);
  float* Pws  = (float*)alloc((size_t)NH * NCHUNK * 4096 * 4);
  float* obuf = (float*)alloc(TH * 4);
  float* x1   = (float*)alloc(TH * 4);
  float* gate = qkv_proj;          // alias (qkv_proj dead after conv)
  float* up   = qkvpost;           // alias (qkvpost dead after phase B)
  u16* g_bf   = (u16*)Wws;         // alias (scan ws dead after phase B)

  auto cvt = [&](const float* s, u16* d, size_t n) {
    int n4 = (int)(n / 4);
    k_cvt<<<dim3((n4 + 255) / 256), 256, 0, stream>>>(s, d, n4);
  };
  cvt(Wq, wq_bf, (size_t)HID * HID);
  cvt(Wk, wk_bf, (size_t)HID * HID);
  cvt(Wv, wv_bf, (size_t)HID * HID);
  cvt(Wout, wout_bf, (size_t)HID * HID);
  cvt(Wgate, wgate_bf, (size_t)INTER * HID);
  cvt(Wup, wup_bf, (size_t)INTER * HID);
  cvt(Wdown, wdown_bf, (size_t)HID * INTER);

  // attn pre-norm
  k_rms<<<dim3(T_SEQ), 256, 0, stream>>>(x, anw, actbf);
  // qkv projections
  k_gemm<<<dim3(HID / 128, T_SEQ / 128, 3), 256, 0, stream>>>(
      actbf, wq_bf, wk_bf, wv_bf, qkv_proj, qkv_proj + TH, qkv_proj + 2 * TH, nullptr,
      T_SEQ, HID, HID);
  // beta
  k_beta<<<dim3(T_SEQ), 256, 0, stream>>>(actbf, Wbeta, betab);
  // conv + silu^2 (+l2norm for q,k)
  k_conv<<<dim3(T_SEQ / 64, NH, 3), 256, 0, stream>>>(qkv_proj, convq, convk, convv, qkvpost);
  // delta scan
  k_phaseA<<<dim3(NCHUNK, NH), 256, 0, stream>>>(
      qkvpost, qkvpost + TH, qkvpost + 2 * TH, betab, Wws, Uvws, Pws);
  k_phaseB<<<dim3(NH), 256, 0, stream>>>(qkvpost, qkvpost + TH, Wws, Uvws, Pws, obuf, out + TH);
  // out-norm + Wout + residual x
  k_rms<<<dim3(T_SEQ), 256, 0, stream>>>(obuf, onw, actbf);
  k_gemm<<<dim3(HID / 128, T_SEQ / 128, 1), 256, 0, stream>>>(
      actbf, wout_bf, wout_bf, wout_bf, x1, x1, x1, x, T_SEQ, HID, HID);
  // MLP
  k_rms<<<dim3(T_SEQ), 256, 0, stream>>>(x1, mnw, actbf);
  k_gemm<<<dim3(INTER / 128, T_SEQ / 128, 2), 256, 0, stream>>>(
      actbf, wgate_bf, wup_bf, wup_bf, gate, up, up, nullptr, T_SEQ, INTER, HID);
  k_swiglu<<<dim3((T_SEQ * INTER / 4) / 256), 256, 0, stream>>>(gate, up, g_bf);
  k_gemm<<<dim3(HID / 128, T_SEQ / 128, 1), 256, 0, stream>>>(
      g_bf, wdown_bf, wdown_bf, wdown_bf, out, out, out, x1, T_SEQ, HID, INTER);
}

// Round 2
// 709.028 us; speedup vs baseline: 1.3801x; 1.3801x over previous
//
#include <hip/hip_runtime.h>
#include <stdint.h>

typedef unsigned short u16;
typedef unsigned int u32;

#define T_SEQ 1024
#define HID   2048
#define NH    32
#define HD    64
#define NCHUNK 16
#define INTER 5632

typedef __attribute__((ext_vector_type(8))) short b16x8;
typedef __attribute__((ext_vector_type(4))) float f32x4;

__device__ inline float bf2f(u16 u) { union { u32 i; float f; } v; v.i = ((u32)u) << 16; return v.f; }
__device__ inline u16 f2bf(float f) {
  union { float f; u32 i; } v; v.f = f;
  u32 u = v.i;
  return (u16)((u + 0x7FFFu + ((u >> 16) & 1u)) >> 16);  // RNE
}
__device__ inline float silu_f(float x) { return x / (1.f + __expf(-x)); }

// async global->LDS, 16B per lane; LDS dest = wave-uniform base + lane*16
typedef __attribute__((address_space(1))) const unsigned int as1_u32;
typedef __attribute__((address_space(3))) unsigned int as3_u32;
__device__ inline void gl_lds16(const void* g, void* l) {
  __builtin_amdgcn_global_load_lds((as1_u32*)g, (as3_u32*)l, 16, 0, 0);
}

// ---------------- fp32 -> bf16 weight conversion ----------------
__global__ __launch_bounds__(256) void k_cvt(const float* __restrict__ s, u16* __restrict__ d, int n4) {
  int i = blockIdx.x * 256 + threadIdx.x;
  if (i < n4) {
    float4 v = ((const float4*)s)[i];
    u32 lo = (u32)f2bf(v.x) | ((u32)f2bf(v.y) << 16);
    u32 hi = (u32)f2bf(v.z) | ((u32)f2bf(v.w) << 16);
    ((uint2*)d)[i] = make_uint2(lo, hi);
  }
}

// ---------------- RMSNorm: fp32 in -> bf16 out ----------------
__global__ __launch_bounds__(256) void k_rms(const float* __restrict__ x, const float* __restrict__ w,
                                             u16* __restrict__ out) {
  int row = blockIdx.x, tid = threadIdx.x;
  const float* xr = x + (size_t)row * HID;
  float4 v0 = ((const float4*)xr)[tid];
  float4 v1 = ((const float4*)xr)[tid + 256];
  float ss = v0.x * v0.x + v0.y * v0.y + v0.z * v0.z + v0.w * v0.w +
             v1.x * v1.x + v1.y * v1.y + v1.z * v1.z + v1.w * v1.w;
  for (int m = 32; m; m >>= 1) ss += __shfl_xor(ss, m, 64);
  __shared__ float wsum[4];
  if ((tid & 63) == 0) wsum[tid >> 6] = ss;
  __syncthreads();
  float tot = wsum[0] + wsum[1] + wsum[2] + wsum[3];
  float sc = rsqrtf(tot / (float)HID + 1e-6f);
  float4 w0 = ((const float4*)w)[tid];
  float4 w1 = ((const float4*)w)[tid + 256];
  u32 lo, hi;
  lo = (u32)f2bf(v0.x * sc * w0.x) | ((u32)f2bf(v0.y * sc * w0.y) << 16);
  hi = (u32)f2bf(v0.z * sc * w0.z) | ((u32)f2bf(v0.w * sc * w0.w) << 16);
  ((uint2*)out)[(size_t)row * 512 + tid] = make_uint2(lo, hi);
  lo = (u32)f2bf(v1.x * sc * w1.x) | ((u32)f2bf(v1.y * sc * w1.y) << 16);
  hi = (u32)f2bf(v1.z * sc * w1.z) | ((u32)f2bf(v1.w * sc * w1.w) << 16);
  ((uint2*)out)[(size_t)row * 512 + tid + 256] = make_uint2(lo, hi);
}

// ---------------- bf16 GEMM: C[M,N] = A[M,K] @ B[N,K]^T (+resid), fp32 out ----------------
// 128x128 tile, BK=32, 4 waves (2x2), m97-style global_load_lds width-16 staging.
__global__ __launch_bounds__(256) void k_gemm(
    const u16* __restrict__ A,
    const u16* __restrict__ B0, const u16* __restrict__ B1, const u16* __restrict__ B2,
    float* __restrict__ C0, float* __restrict__ C1, float* __restrict__ C2,
    const float* __restrict__ resid, int M, int N, int K) {
  const u16* Bp = (blockIdx.z == 0) ? B0 : (blockIdx.z == 1 ? B1 : B2);
  float* Cp = (blockIdx.z == 0) ? C0 : (blockIdx.z == 1 ? C1 : C2);
  __shared__ __align__(16) u16 As[128 * 32];
  __shared__ __align__(16) u16 Bs[128 * 32];
  int tid = threadIdx.x;
  int m0 = blockIdx.y * 128, n0 = blockIdx.x * 128;
  int lane = tid & 63, wv = tid >> 6, wr = wv >> 1, wc = wv & 1;
  int lrow = lane & 15, quad = lane >> 4;
  int lr = lane >> 2, lc = (lane & 3) * 8;  // staging: lane -> (row, col8) within 16-row slab
  f32x4 acc[4][4];
#pragma unroll
  for (int i = 0; i < 4; ++i)
#pragma unroll
    for (int j = 0; j < 4; ++j) acc[i][j] = (f32x4){0.f, 0.f, 0.f, 0.f};

  for (int k0 = 0; k0 < K; k0 += 32) {
    const u16* Ag = A + (size_t)(m0 + wv * 32) * K + k0;
    const u16* Bg = Bp + (size_t)(n0 + wv * 32) * K + k0;
    gl_lds16(Ag + (size_t)lr * K + lc,        &As[(wv * 32) * 32]);
    gl_lds16(Ag + (size_t)(16 + lr) * K + lc, &As[(wv * 32 + 16) * 32]);
    gl_lds16(Bg + (size_t)lr * K + lc,        &Bs[(wv * 32) * 32]);
    gl_lds16(Bg + (size_t)(16 + lr) * K + lc, &Bs[(wv * 32 + 16) * 32]);
    __syncthreads();
    b16x8 af[4], bfr[4];
#pragma unroll
    for (int i = 0; i < 4; ++i) af[i] = *(const b16x8*)&As[(wr * 64 + i * 16 + lrow) * 32 + quad * 8];
#pragma unroll
    for (int j = 0; j < 4; ++j) bfr[j] = *(const b16x8*)&Bs[(wc * 64 + j * 16 + lrow) * 32 + quad * 8];
#pragma unroll
    for (int i = 0; i < 4; ++i)
#pragma unroll
      for (int j = 0; j < 4; ++j)
        acc[i][j] = __builtin_amdgcn_mfma_f32_16x16x32_bf16(af[i], bfr[j], acc[i][j], 0, 0, 0);
    __syncthreads();
  }
#pragma unroll
  for (int i = 0; i < 4; ++i)
#pragma unroll
    for (int j = 0; j < 4; ++j)
#pragma unroll
      for (int r = 0; r < 4; ++r) {
        int row = m0 + wr * 64 + i * 16 + quad * 4 + r;
        int col = n0 + wc * 64 + j * 16 + lrow;
        float val = acc[i][j][r];
        if (resid) val += resid[(size_t)row * N + col];
        Cp[(size_t)row * N + col] = val;
      }
}

// ---------------- beta = sigmoid(h @ Wbeta^T) ----------------
__global__ __launch_bounds__(256) void k_beta(const u16* __restrict__ hbf, const float* __restrict__ Wb,
                                              float* __restrict__ beta) {
  __shared__ __align__(16) float hr[HID];
  __shared__ float red[256];
  int t = blockIdx.x, tid = threadIdx.x;
#pragma unroll
  for (int i = 0; i < 8; ++i) {
    int c = i * 256 + tid;
    hr[c] = bf2f(hbf[(size_t)t * HID + c]);
  }
  __syncthreads();
  int head = tid >> 3, j = tid & 7;
  const float* wrow = Wb + (size_t)head * HID + j * 256;
  const float* hs = hr + j * 256;
  float acc = 0.f;
#pragma unroll 16
  for (int c = 0; c < 256; c += 4) {
    float4 wv = *(const float4*)&wrow[c];
    float4 hv = *(const float4*)&hs[c];
    acc += hv.x * wv.x + hv.y * wv.y + hv.z * wv.z + hv.w * wv.w;
  }
  red[tid] = acc;
  __syncthreads();
  if (tid < 32) {
    float s = 0.f;
#pragma unroll
    for (int i = 0; i < 8; ++i) s += red[tid * 8 + i];
    beta[(size_t)t * NH + tid] = 1.f / (1.f + __expf(-s));
  }
}

// ---------------- causal depthwise conv (K=4) + silu(silu) (+ l2norm for q,k) ----------------
__global__ __launch_bounds__(256) void k_conv(const float* __restrict__ proj,
                                              const float* __restrict__ cw0, const float* __restrict__ cw1,
                                              const float* __restrict__ cw2, float* __restrict__ outp) {
  int z = blockIdx.z;
  const float* src = proj + (size_t)z * T_SEQ * HID;
  float* dst = outp + (size_t)z * T_SEQ * HID;
  const float* cw = (z == 0) ? cw0 : (z == 1 ? cw1 : cw2);
  bool l2 = (z < 2);
  int c = threadIdx.x & 63, wr = threadIdx.x >> 6;
  int head = blockIdx.y;
  int ch = head * 64 + c;
  int t0 = blockIdx.x * 64 + wr * 16;
  float4 w = ((const float4*)cw)[ch];
  float xm3 = (t0 >= 3) ? src[(size_t)(t0 - 3) * HID + ch] : 0.f;
  float xm2 = (t0 >= 2) ? src[(size_t)(t0 - 2) * HID + ch] : 0.f;
  float xm1 = (t0 >= 1) ? src[(size_t)(t0 - 1) * HID + ch] : 0.f;
  for (int i = 0; i < 16; ++i) {
    int t = t0 + i;
    float x0 = src[(size_t)t * HID + ch];
    float zv = xm3 * w.x + xm2 * w.y + xm1 * w.z + x0 * w.w;
    float s = silu_f(silu_f(zv));
    if (l2) {
      float ss = s * s;
      for (int m = 32; m; m >>= 1) ss += __shfl_xor(ss, m, 64);
      float n = sqrtf(ss);
      s = s / fmaxf(n, 1e-12f);
    }
    dst[(size_t)t * HID + ch] = s;
    xm3 = xm2; xm2 = xm1; xm1 = x0;
  }
}

// ---------------- Phase A: per (chunk, head). Produces MFMA-ready bf16 operands:
//   negWbf [s][dk] = -(I+A)^-1 (beta K)     Uvbf [s][dv] = (I+A)^-1 (beta V)
//   Ktbf [dk][s]   Qbf [s][dk]   Pbf [s][s'] = tril(Q K^T) ----------------
__global__ __launch_bounds__(256) void k_phaseA(
    const float* __restrict__ qp, const float* __restrict__ kp, const float* __restrict__ vp,
    const float* __restrict__ beta,
    u16* __restrict__ negWbf, u16* __restrict__ Uvbf, u16* __restrict__ Ktbf,
    u16* __restrict__ Qbf, u16* __restrict__ Pbf) {
  int cx = blockIdx.x, h = blockIdx.y;
  __shared__ __align__(16) u16 Kst[64 * 72];
  __shared__ __align__(16) u16 Qst[64 * 72];
  __shared__ __align__(16) float Af[64 * 68];
  __shared__ float bet[64];
  int tid = threadIdx.x;
  int t0 = cx * 64;
#pragma unroll
  for (int i = 0; i < 16; ++i) {
    int idx = i * 256 + tid, s = idx >> 6, d = idx & 63;
    size_t g = (size_t)(t0 + s) * HID + h * 64 + d;
    Kst[s * 72 + d] = f2bf(kp[g]);
    Qst[s * 72 + d] = f2bf(qp[g]);
  }
  if (tid < 64) bet[tid] = beta[(size_t)(t0 + tid) * NH + h];
  __syncthreads();
  int lane = tid & 63, wv = tid >> 6, lrow = lane & 15, quad = lane >> 4;
  f32x4 accA[4], accP[4];
#pragma unroll
  for (int i = 0; i < 4; ++i) { accA[i] = (f32x4){0.f, 0.f, 0.f, 0.f}; accP[i] = (f32x4){0.f, 0.f, 0.f, 0.f}; }
#pragma unroll
  for (int ks = 0; ks < 2; ++ks) {
    b16x8 bk = *(const b16x8*)&Kst[(wv * 16 + lrow) * 72 + ks * 32 + quad * 8];
#pragma unroll
    for (int i = 0; i < 4; ++i) {
      b16x8 ak = *(const b16x8*)&Kst[(i * 16 + lrow) * 72 + ks * 32 + quad * 8];
      b16x8 aq = *(const b16x8*)&Qst[(i * 16 + lrow) * 72 + ks * 32 + quad * 8];
      accA[i] = __builtin_amdgcn_mfma_f32_16x16x32_bf16(ak, bk, accA[i], 0, 0, 0);
      accP[i] = __builtin_amdgcn_mfma_f32_16x16x32_bf16(aq, bk, accP[i], 0, 0, 0);
    }
  }
  size_t cb2 = ((size_t)h * NCHUNK + cx) * 4096;
#pragma unroll
  for (int i = 0; i < 4; ++i)
#pragma unroll
    for (int r = 0; r < 4; ++r) {
      int srow = i * 16 + quad * 4 + r, col = wv * 16 + lrow;
      Af[srow * 68 + col] = (col < srow) ? accA[i][r] * bet[srow] : 0.f;
      Pbf[cb2 + srow * 64 + col] = f2bf((col <= srow) ? accP[i][r] : 0.f);
    }
  __syncthreads();
  if (wv < 2) {
    // forward substitution (I+A) x = rhs; wave0: rhs=beta*K -> -W; wave1: rhs=beta*V -> Uv
    int c = lane;
    float x[64];
    if (wv == 0) {
#pragma unroll
      for (int s = 0; s < 64; ++s) x[s] = bet[s] * bf2f(Kst[s * 72 + c]);
    } else {
#pragma unroll
      for (int s = 0; s < 64; ++s) x[s] = bet[s] * vp[(size_t)(t0 + s) * HID + h * 64 + c];
    }
#pragma unroll
    for (int s = 1; s < 64; ++s) {
      float a = 0.f;
#pragma unroll
      for (int r = 0; r < (s & ~3); r += 4) {
        float4 av = *(const float4*)&Af[s * 68 + r];
        a += av.x * x[r] + av.y * x[r + 1] + av.z * x[r + 2] + av.w * x[r + 3];
      }
#pragma unroll
      for (int r = (s & ~3); r < s; ++r) a += Af[s * 68 + r] * x[r];
      x[s] -= a;
    }
    if (wv == 0) {
#pragma unroll
      for (int s = 0; s < 64; ++s) negWbf[cb2 + s * 64 + c] = f2bf(-x[s]);
    } else {
#pragma unroll
      for (int s = 0; s < 64; ++s) Uvbf[cb2 + s * 64 + c] = f2bf(x[s]);
    }
  } else if (wv == 2) {
    // coalesced Q export
#pragma unroll
    for (int it = 0; it < 8; ++it) {
      int cidx = it * 64 + lane, s = cidx >> 3, d0 = (cidx & 7) * 8;
      *(uint4*)&Qbf[cb2 + s * 64 + d0] = *(const uint4*)&Qst[s * 72 + d0];
    }
  } else {
    // K transpose export: Ktbf[dk][s]
#pragma unroll
    for (int it = 0; it < 8; ++it) {
      int cidx = it * 64 + lane, d = cidx >> 3, s0 = (cidx & 7) * 8;
      u16 tmp[8];
#pragma unroll
      for (int j = 0; j < 8; ++j) tmp[j] = Kst[(s0 + j) * 72 + d];
      *(uint4*)&Ktbf[cb2 + d * 64 + s0] = *(const uint4*)tmp;
    }
  }
}

// ---------------- Phase B1: serial per head. State in fp32 regs; operands prefetched 1 chunk ahead.
// U = Uv - W S^T ; S += U^T K. Exports U_c (Ut layout) and S_c (bf16) for B2. ----------------
__global__ __launch_bounds__(256) void k_phaseB1(
    const u16* __restrict__ negWbf, const u16* __restrict__ Uvbf, const u16* __restrict__ Ktbf,
    u16* __restrict__ Utws, u16* __restrict__ Sws, float* __restrict__ Sout) {
  int h = blockIdx.x, tid = threadIdx.x;
  __shared__ __align__(16) u16 S0b[2][64 * 72];
  __shared__ __align__(16) u16 Ut[64 * 72];
  int lane = tid & 63, wv = tid >> 6, lrow = lane & 15, quad = lane >> 4;
#pragma unroll
  for (int i = 0; i < 16; ++i) {
    int idx = i * 256 + tid;
    S0b[0][(idx >> 6) * 72 + (idx & 63)] = 0;
  }
  f32x4 aS[4];
#pragma unroll
  for (int i = 0; i < 4; ++i) aS[i] = (f32x4){0.f, 0.f, 0.f, 0.f};

  b16x8 Wf[2][4][2]; b16x8 Ktf[2][2]; u16 Uvr[2][4][4];
  size_t hb = (size_t)h * NCHUNK * 4096;
  {  // preload chunk 0 -> slot 0
    size_t cb2 = hb;
#pragma unroll
    for (int i = 0; i < 4; ++i)
#pragma unroll
      for (int ks = 0; ks < 2; ++ks)
        Wf[0][i][ks] = *(const b16x8*)&negWbf[cb2 + (i * 16 + lrow) * 64 + ks * 32 + quad * 8];
#pragma unroll
    for (int ks = 0; ks < 2; ++ks)
      Ktf[0][ks] = *(const b16x8*)&Ktbf[cb2 + (wv * 16 + lrow) * 64 + ks * 32 + quad * 8];
#pragma unroll
    for (int i = 0; i < 4; ++i)
#pragma unroll
      for (int r = 0; r < 4; ++r)
        Uvr[0][i][r] = Uvbf[cb2 + (i * 16 + quad * 4 + r) * 64 + wv * 16 + lrow];
  }
  __syncthreads();
#pragma unroll
  for (int cx = 0; cx < NCHUNK; ++cx) {
    const int p = cx & 1, q = p ^ 1;
    size_t cb2 = hb + (size_t)cx * 4096;
    if (cx > 0) {  // coalesced export of pre-chunk state for B2
#pragma unroll
      for (int i = 0; i < 2; ++i) {
        int cidx = i * 256 + tid, dv = cidx >> 3, s0 = (cidx & 7) * 8;
        *(uint4*)&Sws[cb2 + dv * 64 + s0] = *(const uint4*)&S0b[p][dv * 72 + s0];
      }
    }
    if (cx + 1 < NCHUNK) {  // prefetch next chunk -> slot q
      size_t cbn = cb2 + 4096;
#pragma unroll
      for (int i = 0; i < 4; ++i)
#pragma unroll
        for (int ks = 0; ks < 2; ++ks)
          Wf[q][i][ks] = *(const b16x8*)&negWbf[cbn + (i * 16 + lrow) * 64 + ks * 32 + quad * 8];
#pragma unroll
      for (int ks = 0; ks < 2; ++ks)
        Ktf[q][ks] = *(const b16x8*)&Ktbf[cbn + (wv * 16 + lrow) * 64 + ks * 32 + quad * 8];
#pragma unroll
      for (int i = 0; i < 4; ++i)
#pragma unroll
        for (int r = 0; r < 4; ++r)
          Uvr[q][i][r] = Uvbf[cbn + (i * 16 + quad * 4 + r) * 64 + wv * 16 + lrow];
    }
    // --- U = Uv + (-W) S^T ---
    f32x4 aU[4];
#pragma unroll
    for (int i = 0; i < 4; ++i)
#pragma unroll
      for (int r = 0; r < 4; ++r) aU[i][r] = bf2f(Uvr[p][i][r]);
#pragma unroll
    for (int ks = 0; ks < 2; ++ks) {
      b16x8 bS = *(const b16x8*)&S0b[p][(wv * 16 + lrow) * 72 + ks * 32 + quad * 8];
#pragma unroll
      for (int i = 0; i < 4; ++i)
        aU[i] = __builtin_amdgcn_mfma_f32_16x16x32_bf16(Wf[p][i][ks], bS, aU[i], 0, 0, 0);
    }
#pragma unroll
    for (int i = 0; i < 4; ++i)
#pragma unroll
      for (int r = 0; r < 4; ++r) {
        int s = i * 16 + quad * 4 + r, dv = wv * 16 + lrow;
        Ut[dv * 72 + s] = f2bf(aU[i][r]);
      }
    __syncthreads();
    // coalesced export of U for B2
#pragma unroll
    for (int i = 0; i < 2; ++i) {
      int cidx = i * 256 + tid, dv = cidx >> 3, s0 = (cidx & 7) * 8;
      *(uint4*)&Utws[cb2 + dv * 64 + s0] = *(const uint4*)&Ut[dv * 72 + s0];
    }
    // --- S += U^T K ---
#pragma unroll
    for (int ks = 0; ks < 2; ++ks) {
#pragma unroll
      for (int i = 0; i < 4; ++i) {
        b16x8 a = *(const b16x8*)&Ut[(i * 16 + lrow) * 72 + ks * 32 + quad * 8];
        aS[i] = __builtin_amdgcn_mfma_f32_16x16x32_bf16(a, Ktf[p][ks], aS[i], 0, 0, 0);
      }
    }
    // stash new state (bf16) into slot q for next chunk's B-frags
#pragma unroll
    for (int i = 0; i < 4; ++i)
#pragma unroll
      for (int r = 0; r < 4; ++r) {
        int dv = i * 16 + quad * 4 + r, dk = wv * 16 + lrow;
        S0b[q][dv * 72 + dk] = f2bf(aS[i][r]);
      }
    __syncthreads();
  }
#pragma unroll
  for (int i = 0; i < 4; ++i)
#pragma unroll
    for (int r = 0; r < 4; ++r) {
      int dv = i * 16 + quad * 4 + r, dk = wv * 16 + lrow;
      Sout[(size_t)h * 4096 + dv * 64 + dk] = aS[i][r];
    }
}

// ---------------- Phase B2: parallel O = Q S^T + P U, all operands register-direct ----------------
__global__ __launch_bounds__(256) void k_phaseB2(
    const u16* __restrict__ Qbf, const u16* __restrict__ Pbf,
    const u16* __restrict__ Utws, const u16* __restrict__ Sws, float* __restrict__ o) {
  int cx = blockIdx.x, h = blockIdx.y, tid = threadIdx.x;
  int lane = tid & 63, wv = tid >> 6, lrow = lane & 15, quad = lane >> 4;
  size_t cb2 = ((size_t)h * NCHUNK + cx) * 4096;
  f32x4 aO[4];
#pragma unroll
  for (int i = 0; i < 4; ++i) aO[i] = (f32x4){0.f, 0.f, 0.f, 0.f};
#pragma unroll
  for (int ks = 0; ks < 2; ++ks) {
    b16x8 Uf = *(const b16x8*)&Utws[cb2 + (wv * 16 + lrow) * 64 + ks * 32 + quad * 8];
#pragma unroll
    for (int i = 0; i < 4; ++i) {
      b16x8 Pf = *(const b16x8*)&Pbf[cb2 + (i * 16 + lrow) * 64 + ks * 32 + quad * 8];
      aO[i] = __builtin_amdgcn_mfma_f32_16x16x32_bf16(Pf, Uf, aO[i], 0, 0, 0);
    }
  }
  if (cx > 0) {
#pragma unroll
    for (int ks = 0; ks < 2; ++ks) {
      b16x8 Sf = *(const b16x8*)&Sws[cb2 + (wv * 16 + lrow) * 64 + ks * 32 + quad * 8];
#pragma unroll
      for (int i = 0; i < 4; ++i) {
        b16x8 Qf = *(const b16x8*)&Qbf[cb2 + (i * 16 + lrow) * 64 + ks * 32 + quad * 8];
        aO[i] = __builtin_amdgcn_mfma_f32_16x16x32_bf16(Qf, Sf, aO[i], 0, 0, 0);
      }
    }
  }
  int t0 = cx * 64;
#pragma unroll
  for (int i = 0; i < 4; ++i)
#pragma unroll
    for (int r = 0; r < 4; ++r)
      o[(size_t)(t0 + i * 16 + quad * 4 + r) * HID + h * 64 + wv * 16 + lrow] = aO[i][r];
}

// ---------------- swiglu ----------------
__global__ __launch_bounds__(256) void k_swiglu(const float* __restrict__ g, const float* __restrict__ u,
                                                u16* __restrict__ d) {
  int i = blockIdx.x * 256 + threadIdx.x;
  float4 gv = ((const float4*)g)[i];
  float4 uv = ((const float4*)u)[i];
  u32 lo = (u32)f2bf(silu_f(gv.x) * uv.x) | ((u32)f2bf(silu_f(gv.y) * uv.y) << 16);
  u32 hi = (u32)f2bf(silu_f(gv.z) * uv.z) | ((u32)f2bf(silu_f(gv.w) * uv.w) << 16);
  ((uint2*)d)[i] = make_uint2(lo, hi);
}

extern "C" void kernel_launch(void* const* d_in, const int* in_sizes, int n_in,
                              void* d_out, int out_size, void* d_ws, size_t ws_size,
                              hipStream_t stream) {
  const float* x     = (const float*)d_in[0];
  const float* anw   = (const float*)d_in[1];
  const float* Wq    = (const float*)d_in[2];
  const float* Wk    = (const float*)d_in[3];
  const float* Wv    = (const float*)d_in[4];
  const float* convq = (const float*)d_in[5];
  const float* convk = (const float*)d_in[6];
  const float* convv = (const float*)d_in[7];
  const float* Wbeta = (const float*)d_in[8];
  const float* onw   = (const float*)d_in[9];
  const float* Wout  = (const float*)d_in[10];
  const float* mnw   = (const float*)d_in[11];
  const float* Wgate = (const float*)d_in[12];
  const float* Wup   = (const float*)d_in[13];
  const float* Wdown = (const float*)d_in[14];
  float* out = (float*)d_out;

  const size_t TH = (size_t)T_SEQ * HID;
  const size_t SCAN = (size_t)NH * NCHUNK * 4096;  // elems per scan buffer
  char* wsb = (char*)d_ws;
  size_t off = 0;
  auto alloc = [&](size_t bytes) -> void* {
    void* p = wsb + off;
    off += (bytes + 255) & ~(size_t)255;
    return p;
  };
  u16* wq_bf    = (u16*)alloc((size_t)HID * HID * 2);
  u16* wk_bf    = (u16*)alloc((size_t)HID * HID * 2);
  u16* wv_bf    = (u16*)alloc((size_t)HID * HID * 2);
  u16* wout_bf  = (u16*)alloc((size_t)HID * HID * 2);
  u16* wgate_bf = (u16*)alloc((size_t)INTER * HID * 2);
  u16* wup_bf   = (u16*)alloc((size_t)INTER * HID * 2);
  u16* wdown_bf = (u16*)alloc((size_t)HID * INTER * 2);
  u16* actbf    = (u16*)alloc(TH * 2);
  float* qkv_proj = (float*)alloc(3 * TH * 4);   // aliased later: obuf, gate
  float* qkvpost  = (float*)alloc(3 * TH * 4);   // aliased later: up
  float* betab    = (float*)alloc((size_t)T_SEQ * NH * 4);
  u16* negWbf = (u16*)alloc(SCAN * 2);           // aliased later by g_bf (needs 3 scan bufs)
  u16* Uvbf   = (u16*)alloc(SCAN * 2);
  u16* Ktbf   = (u16*)alloc(SCAN * 2);
  u16* Qbf    = (u16*)alloc(SCAN * 2);
  u16* Pbf    = (u16*)alloc(SCAN * 2);
  u16* Utws   = (u16*)alloc(SCAN * 2);
  u16* Sws    = (u16*)alloc(SCAN * 2);
  float* x1   = (float*)alloc(TH * 4);
  float* obuf = qkv_proj;   // qkv_proj dead after conv
  float* gate = qkv_proj;   // obuf dead after out-norm
  float* up   = qkvpost;    // qkvpost dead after scan
  u16* g_bf   = negWbf;     // scan buffers dead after B2 (11.5MB < 3x4MB)

  auto cvt = [&](const float* s, u16* d, size_t n) {
    int n4 = (int)(n / 4);
    k_cvt<<<dim3((n4 + 255) / 256), 256, 0, stream>>>(s, d, n4);
  };
  cvt(Wq, wq_bf, (size_t)HID * HID);
  cvt(Wk, wk_bf, (size_t)HID * HID);
  cvt(Wv, wv_bf, (size_t)HID * HID);
  cvt(Wout, wout_bf, (size_t)HID * HID);
  cvt(Wgate, wgate_bf, (size_t)INTER * HID);
  cvt(Wup, wup_bf, (size_t)INTER * HID);
  cvt(Wdown, wdown_bf, (size_t)HID * INTER);

  k_rms<<<dim3(T_SEQ), 256, 0, stream>>>(x, anw, actbf);
  k_gemm<<<dim3(HID / 128, T_SEQ / 128, 3), 256, 0, stream>>>(
      actbf, wq_bf, wk_bf, wv_bf, qkv_proj, qkv_proj + TH, qkv_proj + 2 * TH, nullptr,
      T_SEQ, HID, HID);
  k_beta<<<dim3(T_SEQ), 256, 0, stream>>>(actbf, Wbeta, betab);
  k_conv<<<dim3(T_SEQ / 64, NH, 3), 256, 0, stream>>>(qkv_proj, convq, convk, convv, qkvpost);
  k_phaseA<<<dim3(NCHUNK, NH), 256, 0, stream>>>(
      qkvpost, qkvpost + TH, qkvpost + 2 * TH, betab, negWbf, Uvbf, Ktbf, Qbf, Pbf);
  k_phaseB1<<<dim3(NH), 256, 0, stream>>>(negWbf, Uvbf, Ktbf, Utws, Sws, out + TH);
  k_phaseB2<<<dim3(NCHUNK, NH), 256, 0, stream>>>(Qbf, Pbf, Utws, Sws, obuf);
  k_rms<<<dim3(T_SEQ), 256, 0, stream>>>(obuf, onw, actbf);
  k_gemm<<<dim3(HID / 128, T_SEQ / 128, 1), 256, 0, stream>>>(
      actbf, wout_bf, wout_bf, wout_bf, x1, x1, x1, x, T_SEQ, HID, HID);
  k_rms<<<dim3(T_SEQ), 256, 0, stream>>>(x1, mnw, actbf);
  k_gemm<<<dim3(INTER / 128, T_SEQ / 128, 2), 256, 0, stream>>>(
      actbf, wgate_bf, wup_bf, wup_bf, gate, up, up, nullptr, T_SEQ, INTER, HID);
  k_swiglu<<<dim3((T_SEQ * INTER / 4) / 256), 256, 0, stream>>>(gate, up, g_bf);
  k_gemm<<<dim3(HID / 128, T_SEQ / 128, 1), 256, 0, stream>>>(
      g_bf, wdown_bf, wdown_bf, wdown_bf, out, out, out, x1, T_SEQ, HID, INTER);
}

// Round 3
// 706.332 us; speedup vs baseline: 1.3854x; 1.0038x over previous
//
#include <hip/hip_runtime.h>
#include <stdint.h>

typedef unsigned short u16;
typedef unsigned int u32;

#define T_SEQ 1024
#define HID   2048
#define NH    32
#define HD    64
#define NCHUNK 16
#define INTER 5632

typedef __attribute__((ext_vector_type(8))) short b16x8;
typedef __attribute__((ext_vector_type(4))) float f32x4;

__device__ inline float bf2f(u16 u) { union { u32 i; float f; } v; v.i = ((u32)u) << 16; return v.f; }
__device__ inline u16 f2bf(float f) {
  union { float f; u32 i; } v; v.f = f;
  u32 u = v.i;
  return (u16)((u + 0x7FFFu + ((u >> 16) & 1u)) >> 16);  // RNE
}
__device__ inline float silu_f(float x) { return x / (1.f + __expf(-x)); }

typedef __attribute__((address_space(1))) const unsigned int as1_u32;
typedef __attribute__((address_space(3))) unsigned int as3_u32;
__device__ inline void gl_lds16(const void* g, void* l) {
  __builtin_amdgcn_global_load_lds((as1_u32*)g, (as3_u32*)l, 16, 0, 0);
}

// ---------------- fp32 -> bf16 all-weights conversion (one launch) ----------------
__global__ __launch_bounds__(256) void k_cvt_all(
    const float* __restrict__ s0, const float* __restrict__ s1, const float* __restrict__ s2,
    const float* __restrict__ s3, const float* __restrict__ s4, const float* __restrict__ s5,
    const float* __restrict__ s6,
    u16* __restrict__ d0, u16* __restrict__ d1, u16* __restrict__ d2, u16* __restrict__ d3,
    u16* __restrict__ d4, u16* __restrict__ d5, u16* __restrict__ d6) {
  int z = blockIdx.y;
  int n4 = (z < 4) ? (HID * HID / 4) : (INTER * HID / 4);
  int i = blockIdx.x * 256 + threadIdx.x;
  if (i >= n4) return;
  const float* s = (z == 0) ? s0 : (z == 1) ? s1 : (z == 2) ? s2 : (z == 3) ? s3
                   : (z == 4) ? s4 : (z == 5) ? s5 : s6;
  u16* d = (z == 0) ? d0 : (z == 1) ? d1 : (z == 2) ? d2 : (z == 3) ? d3
           : (z == 4) ? d4 : (z == 5) ? d5 : d6;
  float4 v = ((const float4*)s)[i];
  u32 lo = (u32)f2bf(v.x) | ((u32)f2bf(v.y) << 16);
  u32 hi = (u32)f2bf(v.z) | ((u32)f2bf(v.w) << 16);
  ((uint2*)d)[i] = make_uint2(lo, hi);
}

// ---------------- RMSNorm: fp32 in -> bf16 out ----------------
__global__ __launch_bounds__(256) void k_rms(const float* __restrict__ x, const float* __restrict__ w,
                                             u16* __restrict__ out) {
  int row = blockIdx.x, tid = threadIdx.x;
  const float* xr = x + (size_t)row * HID;
  float4 v0 = ((const float4*)xr)[tid];
  float4 v1 = ((const float4*)xr)[tid + 256];
  float ss = v0.x * v0.x + v0.y * v0.y + v0.z * v0.z + v0.w * v0.w +
             v1.x * v1.x + v1.y * v1.y + v1.z * v1.z + v1.w * v1.w;
  for (int m = 32; m; m >>= 1) ss += __shfl_xor(ss, m, 64);
  __shared__ float wsum[4];
  if ((tid & 63) == 0) wsum[tid >> 6] = ss;
  __syncthreads();
  float tot = wsum[0] + wsum[1] + wsum[2] + wsum[3];
  float sc = rsqrtf(tot / (float)HID + 1e-6f);
  float4 w0 = ((const float4*)w)[tid];
  float4 w1 = ((const float4*)w)[tid + 256];
  u32 lo, hi;
  lo = (u32)f2bf(v0.x * sc * w0.x) | ((u32)f2bf(v0.y * sc * w0.y) << 16);
  hi = (u32)f2bf(v0.z * sc * w0.z) | ((u32)f2bf(v0.w * sc * w0.w) << 16);
  ((uint2*)out)[(size_t)row * 512 + tid] = make_uint2(lo, hi);
  lo = (u32)f2bf(v1.x * sc * w1.x) | ((u32)f2bf(v1.y * sc * w1.y) << 16);
  hi = (u32)f2bf(v1.z * sc * w1.z) | ((u32)f2bf(v1.w * sc * w1.w) << 16);
  ((uint2*)out)[(size_t)row * 512 + tid + 256] = make_uint2(lo, hi);
}

// ---------------- split-K bf16 GEMM, XOR-swizzled LDS, atomicAdd fp32 epilogue ----------------
// C[M,N] += A[M,K] @ B[N,K]^T (slice) ; resid added by slice 0. C must be pre-zeroed.
__global__ __launch_bounds__(256) void k_gemm_sk(
    const u16* __restrict__ A,
    const u16* __restrict__ B0, const u16* __restrict__ B1, const u16* __restrict__ B2,
    float* __restrict__ C0, float* __restrict__ C1, float* __restrict__ C2,
    const float* __restrict__ resid, int M, int N, int Kf, int KS, int nslice) {
  int mat = blockIdx.z / nslice, slice = blockIdx.z % nslice;
  const u16* Bp = (mat == 0) ? B0 : (mat == 1 ? B1 : B2);
  float* Cp = (mat == 0) ? C0 : (mat == 1 ? C1 : C2);
  __shared__ __align__(16) u16 As[128 * 32];
  __shared__ __align__(16) u16 Bs[128 * 32];
  int tid = threadIdx.x;
  int m0 = blockIdx.y * 128, n0 = blockIdx.x * 128;
  int lane = tid & 63, wv = tid >> 6, wr = wv >> 1, wc = wv & 1;
  int lrow = lane & 15, quad = lane >> 4;
  int lr = lane >> 2;
  int lc = (((lane & 3) ^ ((lr >> 1) & 3)) * 8);  // XOR-swizzled source chunk
  int xq = quad ^ ((lrow >> 1) & 3);              // XOR-swizzled read chunk
  f32x4 acc[4][4];
#pragma unroll
  for (int i = 0; i < 4; ++i)
#pragma unroll
    for (int j = 0; j < 4; ++j) acc[i][j] = (f32x4){0.f, 0.f, 0.f, 0.f};

  int kb = slice * KS, ke = kb + KS;
  for (int k0 = kb; k0 < ke; k0 += 32) {
    const u16* Ag = A + (size_t)(m0 + wv * 32) * Kf + k0;
    const u16* Bg = Bp + (size_t)(n0 + wv * 32) * Kf + k0;
    gl_lds16(Ag + (size_t)lr * Kf + lc,        &As[(wv * 32) * 32]);
    gl_lds16(Ag + (size_t)(16 + lr) * Kf + lc, &As[(wv * 32 + 16) * 32]);
    gl_lds16(Bg + (size_t)lr * Kf + lc,        &Bs[(wv * 32) * 32]);
    gl_lds16(Bg + (size_t)(16 + lr) * Kf + lc, &Bs[(wv * 32 + 16) * 32]);
    __syncthreads();
    b16x8 af[4], bfr[4];
#pragma unroll
    for (int i = 0; i < 4; ++i) af[i] = *(const b16x8*)&As[(wr * 64 + i * 16 + lrow) * 32 + xq * 8];
#pragma unroll
    for (int j = 0; j < 4; ++j) bfr[j] = *(const b16x8*)&Bs[(wc * 64 + j * 16 + lrow) * 32 + xq * 8];
#pragma unroll
    for (int i = 0; i < 4; ++i)
#pragma unroll
      for (int j = 0; j < 4; ++j)
        acc[i][j] = __builtin_amdgcn_mfma_f32_16x16x32_bf16(af[i], bfr[j], acc[i][j], 0, 0, 0);
    __syncthreads();
  }
#pragma unroll
  for (int i = 0; i < 4; ++i)
#pragma unroll
    for (int j = 0; j < 4; ++j)
#pragma unroll
      for (int r = 0; r < 4; ++r) {
        int row = m0 + wr * 64 + i * 16 + quad * 4 + r;
        int col = n0 + wc * 64 + j * 16 + lrow;
        float val = acc[i][j][r];
        if (slice == 0 && resid) val += resid[(size_t)row * N + col];
        atomicAdd(&Cp[(size_t)row * N + col], val);
      }
}

// ---------------- fused gate/up GEMM + swiglu: g_bf = bf16(silu(A Wg^T) * (A Wu^T)) ----------------
__global__ __launch_bounds__(256) void k_gemm_gu(
    const u16* __restrict__ A, const u16* __restrict__ Bg, const u16* __restrict__ Bu,
    u16* __restrict__ D) {
  __shared__ __align__(16) u16 As[128 * 32];
  __shared__ __align__(16) u16 Gs[128 * 32];
  __shared__ __align__(16) u16 Us[128 * 32];
  int tid = threadIdx.x;
  int m0 = blockIdx.y * 128, n0 = blockIdx.x * 128;
  int lane = tid & 63, wv = tid >> 6, wr = wv >> 1, wc = wv & 1;
  int lrow = lane & 15, quad = lane >> 4;
  int lr = lane >> 2;
  int lc = (((lane & 3) ^ ((lr >> 1) & 3)) * 8);
  int xq = quad ^ ((lrow >> 1) & 3);
  f32x4 ag[4][4], au[4][4];
#pragma unroll
  for (int i = 0; i < 4; ++i)
#pragma unroll
    for (int j = 0; j < 4; ++j) { ag[i][j] = (f32x4){0.f, 0.f, 0.f, 0.f}; au[i][j] = (f32x4){0.f, 0.f, 0.f, 0.f}; }

  for (int k0 = 0; k0 < HID; k0 += 32) {
    const u16* Ap = A + (size_t)(m0 + wv * 32) * HID + k0;
    const u16* Gp = Bg + (size_t)(n0 + wv * 32) * HID + k0;
    const u16* Up = Bu + (size_t)(n0 + wv * 32) * HID + k0;
    gl_lds16(Ap + (size_t)lr * HID + lc,        &As[(wv * 32) * 32]);
    gl_lds16(Ap + (size_t)(16 + lr) * HID + lc, &As[(wv * 32 + 16) * 32]);
    gl_lds16(Gp + (size_t)lr * HID + lc,        &Gs[(wv * 32) * 32]);
    gl_lds16(Gp + (size_t)(16 + lr) * HID + lc, &Gs[(wv * 32 + 16) * 32]);
    gl_lds16(Up + (size_t)lr * HID + lc,        &Us[(wv * 32) * 32]);
    gl_lds16(Up + (size_t)(16 + lr) * HID + lc, &Us[(wv * 32 + 16) * 32]);
    __syncthreads();
    b16x8 af[4], gf[4], uf[4];
#pragma unroll
    for (int i = 0; i < 4; ++i) af[i] = *(const b16x8*)&As[(wr * 64 + i * 16 + lrow) * 32 + xq * 8];
#pragma unroll
    for (int j = 0; j < 4; ++j) gf[j] = *(const b16x8*)&Gs[(wc * 64 + j * 16 + lrow) * 32 + xq * 8];
#pragma unroll
    for (int j = 0; j < 4; ++j) uf[j] = *(const b16x8*)&Us[(wc * 64 + j * 16 + lrow) * 32 + xq * 8];
#pragma unroll
    for (int i = 0; i < 4; ++i)
#pragma unroll
      for (int j = 0; j < 4; ++j) {
        ag[i][j] = __builtin_amdgcn_mfma_f32_16x16x32_bf16(af[i], gf[j], ag[i][j], 0, 0, 0);
        au[i][j] = __builtin_amdgcn_mfma_f32_16x16x32_bf16(af[i], uf[j], au[i][j], 0, 0, 0);
      }
    __syncthreads();
  }
#pragma unroll
  for (int i = 0; i < 4; ++i)
#pragma unroll
    for (int j = 0; j < 4; ++j)
#pragma unroll
      for (int r = 0; r < 4; ++r) {
        int row = m0 + wr * 64 + i * 16 + quad * 4 + r;
        int col = n0 + wc * 64 + j * 16 + lrow;
        D[(size_t)row * INTER + col] = f2bf(silu_f(ag[i][j][r]) * au[i][j][r]);
      }
}

// ---------------- beta = sigmoid(h @ Wbeta^T) ----------------
__global__ __launch_bounds__(256) void k_beta(const u16* __restrict__ hbf, const float* __restrict__ Wb,
                                              float* __restrict__ beta) {
  __shared__ __align__(16) float hr[HID];
  __shared__ float red[256];
  int t = blockIdx.x, tid = threadIdx.x;
#pragma unroll
  for (int i = 0; i < 8; ++i) {
    int c = i * 256 + tid;
    hr[c] = bf2f(hbf[(size_t)t * HID + c]);
  }
  __syncthreads();
  int head = tid >> 3, j = tid & 7;
  const float* wrow = Wb + (size_t)head * HID + j * 256;
  const float* hs = hr + j * 256;
  float acc = 0.f;
#pragma unroll 16
  for (int c = 0; c < 256; c += 4) {
    float4 wv = *(const float4*)&wrow[c];
    float4 hv = *(const float4*)&hs[c];
    acc += hv.x * wv.x + hv.y * wv.y + hv.z * wv.z + hv.w * wv.w;
  }
  red[tid] = acc;
  __syncthreads();
  if (tid < 32) {
    float s = 0.f;
#pragma unroll
    for (int i = 0; i < 8; ++i) s += red[tid * 8 + i];
    beta[(size_t)t * NH + tid] = 1.f / (1.f + __expf(-s));
  }
}

// ---------------- causal depthwise conv (K=4) + silu(silu) (+ l2norm for q,k) ----------------
__global__ __launch_bounds__(256) void k_conv(const float* __restrict__ proj,
                                              const float* __restrict__ cw0, const float* __restrict__ cw1,
                                              const float* __restrict__ cw2, float* __restrict__ outp) {
  int z = blockIdx.z;
  const float* src = proj + (size_t)z * T_SEQ * HID;
  float* dst = outp + (size_t)z * T_SEQ * HID;
  const float* cw = (z == 0) ? cw0 : (z == 1 ? cw1 : cw2);
  bool l2 = (z < 2);
  int c = threadIdx.x & 63, wr = threadIdx.x >> 6;
  int head = blockIdx.y;
  int ch = head * 64 + c;
  int t0 = blockIdx.x * 64 + wr * 16;
  float4 w = ((const float4*)cw)[ch];
  float xm3 = (t0 >= 3) ? src[(size_t)(t0 - 3) * HID + ch] : 0.f;
  float xm2 = (t0 >= 2) ? src[(size_t)(t0 - 2) * HID + ch] : 0.f;
  float xm1 = (t0 >= 1) ? src[(size_t)(t0 - 1) * HID + ch] : 0.f;
  for (int i = 0; i < 16; ++i) {
    int t = t0 + i;
    float x0 = src[(size_t)t * HID + ch];
    float zv = xm3 * w.x + xm2 * w.y + xm1 * w.z + x0 * w.w;
    float s = silu_f(silu_f(zv));
    if (l2) {
      float ss = s * s;
      for (int m = 32; m; m >>= 1) ss += __shfl_xor(ss, m, 64);
      float n = sqrtf(ss);
      s = s / fmaxf(n, 1e-12f);
    }
    dst[(size_t)t * HID + ch] = s;
    xm3 = xm2; xm2 = xm1; xm1 = x0;
  }
}

// ---------------- Phase A ----------------
__global__ __launch_bounds__(256) void k_phaseA(
    const float* __restrict__ qp, const float* __restrict__ kp, const float* __restrict__ vp,
    const float* __restrict__ beta,
    u16* __restrict__ negWbf, u16* __restrict__ Uvbf, u16* __restrict__ Ktbf,
    u16* __restrict__ Qbf, u16* __restrict__ Pbf) {
  int cx = blockIdx.x, h = blockIdx.y;
  __shared__ __align__(16) u16 Kst[64 * 72];
  __shared__ __align__(16) u16 Qst[64 * 72];
  __shared__ __align__(16) float Af[64 * 68];
  __shared__ float bet[64];
  int tid = threadIdx.x;
  int t0 = cx * 64;
#pragma unroll
  for (int i = 0; i < 16; ++i) {
    int idx = i * 256 + tid, s = idx >> 6, d = idx & 63;
    size_t g = (size_t)(t0 + s) * HID + h * 64 + d;
    Kst[s * 72 + d] = f2bf(kp[g]);
    Qst[s * 72 + d] = f2bf(qp[g]);
  }
  if (tid < 64) bet[tid] = beta[(size_t)(t0 + tid) * NH + h];
  __syncthreads();
  int lane = tid & 63, wv = tid >> 6, lrow = lane & 15, quad = lane >> 4;
  f32x4 accA[4], accP[4];
#pragma unroll
  for (int i = 0; i < 4; ++i) { accA[i] = (f32x4){0.f, 0.f, 0.f, 0.f}; accP[i] = (f32x4){0.f, 0.f, 0.f, 0.f}; }
#pragma unroll
  for (int ks = 0; ks < 2; ++ks) {
    b16x8 bk = *(const b16x8*)&Kst[(wv * 16 + lrow) * 72 + ks * 32 + quad * 8];
#pragma unroll
    for (int i = 0; i < 4; ++i) {
      b16x8 ak = *(const b16x8*)&Kst[(i * 16 + lrow) * 72 + ks * 32 + quad * 8];
      b16x8 aq = *(const b16x8*)&Qst[(i * 16 + lrow) * 72 + ks * 32 + quad * 8];
      accA[i] = __builtin_amdgcn_mfma_f32_16x16x32_bf16(ak, bk, accA[i], 0, 0, 0);
      accP[i] = __builtin_amdgcn_mfma_f32_16x16x32_bf16(aq, bk, accP[i], 0, 0, 0);
    }
  }
  size_t cb2 = ((size_t)h * NCHUNK + cx) * 4096;
#pragma unroll
  for (int i = 0; i < 4; ++i)
#pragma unroll
    for (int r = 0; r < 4; ++r) {
      int srow = i * 16 + quad * 4 + r, col = wv * 16 + lrow;
      Af[srow * 68 + col] = (col < srow) ? accA[i][r] * bet[srow] : 0.f;
      Pbf[cb2 + srow * 64 + col] = f2bf((col <= srow) ? accP[i][r] : 0.f);
    }
  __syncthreads();
  if (wv < 2) {
    int c = lane;
    float x[64];
    if (wv == 0) {
#pragma unroll
      for (int s = 0; s < 64; ++s) x[s] = bet[s] * bf2f(Kst[s * 72 + c]);
    } else {
#pragma unroll
      for (int s = 0; s < 64; ++s) x[s] = bet[s] * vp[(size_t)(t0 + s) * HID + h * 64 + c];
    }
#pragma unroll
    for (int s = 1; s < 64; ++s) {
      float a = 0.f;
#pragma unroll
      for (int r = 0; r < (s & ~3); r += 4) {
        float4 av = *(const float4*)&Af[s * 68 + r];
        a += av.x * x[r] + av.y * x[r + 1] + av.z * x[r + 2] + av.w * x[r + 3];
      }
#pragma unroll
      for (int r = (s & ~3); r < s; ++r) a += Af[s * 68 + r] * x[r];
      x[s] -= a;
    }
    if (wv == 0) {
#pragma unroll
      for (int s = 0; s < 64; ++s) negWbf[cb2 + s * 64 + c] = f2bf(-x[s]);
    } else {
#pragma unroll
      for (int s = 0; s < 64; ++s) Uvbf[cb2 + s * 64 + c] = f2bf(x[s]);
    }
  } else if (wv == 2) {
#pragma unroll
    for (int it = 0; it < 8; ++it) {
      int cidx = it * 64 + lane, s = cidx >> 3, d0 = (cidx & 7) * 8;
      *(uint4*)&Qbf[cb2 + s * 64 + d0] = *(const uint4*)&Qst[s * 72 + d0];
    }
  } else {
#pragma unroll
    for (int it = 0; it < 8; ++it) {
      int cidx = it * 64 + lane, d = cidx >> 3, s0 = (cidx & 7) * 8;
      u16 tmp[8];
#pragma unroll
      for (int j = 0; j < 8; ++j) tmp[j] = Kst[(s0 + j) * 72 + d];
      *(uint4*)&Ktbf[cb2 + d * 64 + s0] = *(const uint4*)tmp;
    }
  }
}

// ---------------- Phase B1: serial per head ----------------
__global__ __launch_bounds__(256) void k_phaseB1(
    const u16* __restrict__ negWbf, const u16* __restrict__ Uvbf, const u16* __restrict__ Ktbf,
    u16* __restrict__ Utws, u16* __restrict__ Sws, float* __restrict__ Sout) {
  int h = blockIdx.x, tid = threadIdx.x;
  __shared__ __align__(16) u16 S0b[2][64 * 72];
  __shared__ __align__(16) u16 Ut[64 * 72];
  int lane = tid & 63, wv = tid >> 6, lrow = lane & 15, quad = lane >> 4;
#pragma unroll
  for (int i = 0; i < 16; ++i) {
    int idx = i * 256 + tid;
    S0b[0][(idx >> 6) * 72 + (idx & 63)] = 0;
  }
  f32x4 aS[4];
#pragma unroll
  for (int i = 0; i < 4; ++i) aS[i] = (f32x4){0.f, 0.f, 0.f, 0.f};

  b16x8 Wf[2][4][2]; b16x8 Ktf[2][2]; u16 Uvr[2][4][4];
  size_t hb = (size_t)h * NCHUNK * 4096;
  {
    size_t cb2 = hb;
#pragma unroll
    for (int i = 0; i < 4; ++i)
#pragma unroll
      for (int ks = 0; ks < 2; ++ks)
        Wf[0][i][ks] = *(const b16x8*)&negWbf[cb2 + (i * 16 + lrow) * 64 + ks * 32 + quad * 8];
#pragma unroll
    for (int ks = 0; ks < 2; ++ks)
      Ktf[0][ks] = *(const b16x8*)&Ktbf[cb2 + (wv * 16 + lrow) * 64 + ks * 32 + quad * 8];
#pragma unroll
    for (int i = 0; i < 4; ++i)
#pragma unroll
      for (int r = 0; r < 4; ++r)
        Uvr[0][i][r] = Uvbf[cb2 + (i * 16 + quad * 4 + r) * 64 + wv * 16 + lrow];
  }
  __syncthreads();
#pragma unroll
  for (int cx = 0; cx < NCHUNK; ++cx) {
    const int p = cx & 1, q = p ^ 1;
    size_t cb2 = hb + (size_t)cx * 4096;
    if (cx > 0) {
#pragma unroll
      for (int i = 0; i < 2; ++i) {
        int cidx = i * 256 + tid, dv = cidx >> 3, s0 = (cidx & 7) * 8;
        *(uint4*)&Sws[cb2 + dv * 64 + s0] = *(const uint4*)&S0b[p][dv * 72 + s0];
      }
    }
    if (cx + 1 < NCHUNK) {
      size_t cbn = cb2 + 4096;
#pragma unroll
      for (int i = 0; i < 4; ++i)
#pragma unroll
        for (int ks = 0; ks < 2; ++ks)
          Wf[q][i][ks] = *(const b16x8*)&negWbf[cbn + (i * 16 + lrow) * 64 + ks * 32 + quad * 8];
#pragma unroll
      for (int ks = 0; ks < 2; ++ks)
        Ktf[q][ks] = *(const b16x8*)&Ktbf[cbn + (wv * 16 + lrow) * 64 + ks * 32 + quad * 8];
#pragma unroll
      for (int i = 0; i < 4; ++i)
#pragma unroll
        for (int r = 0; r < 4; ++r)
          Uvr[q][i][r] = Uvbf[cbn + (i * 16 + quad * 4 + r) * 64 + wv * 16 + lrow];
    }
    f32x4 aU[4];
#pragma unroll
    for (int i = 0; i < 4; ++i)
#pragma unroll
      for (int r = 0; r < 4; ++r) aU[i][r] = bf2f(Uvr[p][i][r]);
#pragma unroll
    for (int ks = 0; ks < 2; ++ks) {
      b16x8 bS = *(const b16x8*)&S0b[p][(wv * 16 + lrow) * 72 + ks * 32 + quad * 8];
#pragma unroll
      for (int i = 0; i < 4; ++i)
        aU[i] = __builtin_amdgcn_mfma_f32_16x16x32_bf16(Wf[p][i][ks], bS, aU[i], 0, 0, 0);
    }
#pragma unroll
    for (int i = 0; i < 4; ++i)
#pragma unroll
      for (int r = 0; r < 4; ++r) {
        int s = i * 16 + quad * 4 + r, dv = wv * 16 + lrow;
        Ut[dv * 72 + s] = f2bf(aU[i][r]);
      }
    __syncthreads();
#pragma unroll
    for (int i = 0; i < 2; ++i) {
      int cidx = i * 256 + tid, dv = cidx >> 3, s0 = (cidx & 7) * 8;
      *(uint4*)&Utws[cb2 + dv * 64 + s0] = *(const uint4*)&Ut[dv * 72 + s0];
    }
#pragma unroll
    for (int ks = 0; ks < 2; ++ks) {
#pragma unroll
      for (int i = 0; i < 4; ++i) {
        b16x8 a = *(const b16x8*)&Ut[(i * 16 + lrow) * 72 + ks * 32 + quad * 8];
        aS[i] = __builtin_amdgcn_mfma_f32_16x16x32_bf16(a, Ktf[p][ks], aS[i], 0, 0, 0);
      }
    }
#pragma unroll
    for (int i = 0; i < 4; ++i)
#pragma unroll
      for (int r = 0; r < 4; ++r) {
        int dv = i * 16 + quad * 4 + r, dk = wv * 16 + lrow;
        S0b[q][dv * 72 + dk] = f2bf(aS[i][r]);
      }
    __syncthreads();
  }
#pragma unroll
  for (int i = 0; i < 4; ++i)
#pragma unroll
    for (int r = 0; r < 4; ++r) {
      int dv = i * 16 + quad * 4 + r, dk = wv * 16 + lrow;
      Sout[(size_t)h * 4096 + dv * 64 + dk] = aS[i][r];
    }
}

// ---------------- Phase B2: parallel O = Q S^T + P U ----------------
__global__ __launch_bounds__(256) void k_phaseB2(
    const u16* __restrict__ Qbf, const u16* __restrict__ Pbf,
    const u16* __restrict__ Utws, const u16* __restrict__ Sws, float* __restrict__ o) {
  int cx = blockIdx.x, h = blockIdx.y, tid = threadIdx.x;
  int lane = tid & 63, wv = tid >> 6, lrow = lane & 15, quad = lane >> 4;
  size_t cb2 = ((size_t)h * NCHUNK + cx) * 4096;
  f32x4 aO[4];
#pragma unroll
  for (int i = 0; i < 4; ++i) aO[i] = (f32x4){0.f, 0.f, 0.f, 0.f};
#pragma unroll
  for (int ks = 0; ks < 2; ++ks) {
    b16x8 Uf = *(const b16x8*)&Utws[cb2 + (wv * 16 + lrow) * 64 + ks * 32 + quad * 8];
#pragma unroll
    for (int i = 0; i < 4; ++i) {
      b16x8 Pf = *(const b16x8*)&Pbf[cb2 + (i * 16 + lrow) * 64 + ks * 32 + quad * 8];
      aO[i] = __builtin_amdgcn_mfma_f32_16x16x32_bf16(Pf, Uf, aO[i], 0, 0, 0);
    }
  }
  if (cx > 0) {
#pragma unroll
    for (int ks = 0; ks < 2; ++ks) {
      b16x8 Sf = *(const b16x8*)&Sws[cb2 + (wv * 16 + lrow) * 64 + ks * 32 + quad * 8];
#pragma unroll
      for (int i = 0; i < 4; ++i) {
        b16x8 Qf = *(const b16x8*)&Qbf[cb2 + (i * 16 + lrow) * 64 + ks * 32 + quad * 8];
        aO[i] = __builtin_amdgcn_mfma_f32_16x16x32_bf16(Qf, Sf, aO[i], 0, 0, 0);
      }
    }
  }
  int t0 = cx * 64;
#pragma unroll
  for (int i = 0; i < 4; ++i)
#pragma unroll
    for (int r = 0; r < 4; ++r)
      o[(size_t)(t0 + i * 16 + quad * 4 + r) * HID + h * 64 + wv * 16 + lrow] = aO[i][r];
}

extern "C" void kernel_launch(void* const* d_in, const int* in_sizes, int n_in,
                              void* d_out, int out_size, void* d_ws, size_t ws_size,
                              hipStream_t stream) {
  const float* x     = (const float*)d_in[0];
  const float* anw   = (const float*)d_in[1];
  const float* Wq    = (const float*)d_in[2];
  const float* Wk    = (const float*)d_in[3];
  const float* Wv    = (const float*)d_in[4];
  const float* convq = (const float*)d_in[5];
  const float* convk = (const float*)d_in[6];
  const float* convv = (const float*)d_in[7];
  const float* Wbeta = (const float*)d_in[8];
  const float* onw   = (const float*)d_in[9];
  const float* Wout  = (const float*)d_in[10];
  const float* mnw   = (const float*)d_in[11];
  const float* Wgate = (const float*)d_in[12];
  const float* Wup   = (const float*)d_in[13];
  const float* Wdown = (const float*)d_in[14];
  float* out = (float*)d_out;

  const size_t TH = (size_t)T_SEQ * HID;
  const size_t SCAN = (size_t)NH * NCHUNK * 4096;
  char* wsb = (char*)d_ws;
  size_t off = 0;
  auto alloc = [&](size_t bytes) -> void* {
    void* p = wsb + off;
    off += (bytes + 255) & ~(size_t)255;
    return p;
  };
  u16* wq_bf    = (u16*)alloc((size_t)HID * HID * 2);
  u16* wk_bf    = (u16*)alloc((size_t)HID * HID * 2);
  u16* wv_bf    = (u16*)alloc((size_t)HID * HID * 2);
  u16* wout_bf  = (u16*)alloc((size_t)HID * HID * 2);
  u16* wgate_bf = (u16*)alloc((size_t)INTER * HID * 2);
  u16* wup_bf   = (u16*)alloc((size_t)INTER * HID * 2);
  u16* wdown_bf = (u16*)alloc((size_t)HID * INTER * 2);
  u16* actbf    = (u16*)alloc(TH * 2);
  float* qkv_proj = (float*)alloc(3 * TH * 4);   // aliased later: obuf
  float* qkvpost  = (float*)alloc(3 * TH * 4);
  float* betab    = (float*)alloc((size_t)T_SEQ * NH * 4);
  u16* negWbf = (u16*)alloc(SCAN * 2);           // aliased later by g_bf
  u16* Uvbf   = (u16*)alloc(SCAN * 2);
  u16* Ktbf   = (u16*)alloc(SCAN * 2);
  u16* Qbf    = (u16*)alloc(SCAN * 2);
  u16* Pbf    = (u16*)alloc(SCAN * 2);
  u16* Utws   = (u16*)alloc(SCAN * 2);
  u16* Sws    = (u16*)alloc(SCAN * 2);
  float* x1   = (float*)alloc(TH * 4);
  float* obuf = qkv_proj;   // qkv_proj dead after conv
  u16* g_bf   = negWbf;     // scan buffers dead after B2 (11.5MB < 3x4.19MB)

  // ---- all weight conversions in one launch ----
  k_cvt_all<<<dim3(INTER * HID / 4 / 256, 7), 256, 0, stream>>>(
      Wq, Wk, Wv, Wout, Wgate, Wup, Wdown,
      wq_bf, wk_bf, wv_bf, wout_bf, wgate_bf, wup_bf, wdown_bf);

  k_rms<<<dim3(T_SEQ), 256, 0, stream>>>(x, anw, actbf);
  // qkv projections: splitK=2, atomic into zeroed qkv_proj
  hipMemsetAsync(qkv_proj, 0, 3 * TH * 4, stream);
  k_gemm_sk<<<dim3(HID / 128, T_SEQ / 128, 6), 256, 0, stream>>>(
      actbf, wq_bf, wk_bf, wv_bf, qkv_proj, qkv_proj + TH, qkv_proj + 2 * TH, nullptr,
      T_SEQ, HID, HID, HID / 2, 2);
  k_beta<<<dim3(T_SEQ), 256, 0, stream>>>(actbf, Wbeta, betab);
  k_conv<<<dim3(T_SEQ / 64, NH, 3), 256, 0, stream>>>(qkv_proj, convq, convk, convv, qkvpost);
  k_phaseA<<<dim3(NCHUNK, NH), 256, 0, stream>>>(
      qkvpost, qkvpost + TH, qkvpost + 2 * TH, betab, negWbf, Uvbf, Ktbf, Qbf, Pbf);
  k_phaseB1<<<dim3(NH), 256, 0, stream>>>(negWbf, Uvbf, Ktbf, Utws, Sws, out + TH);
  k_phaseB2<<<dim3(NCHUNK, NH), 256, 0, stream>>>(Qbf, Pbf, Utws, Sws, obuf);
  k_rms<<<dim3(T_SEQ), 256, 0, stream>>>(obuf, onw, actbf);
  // out projection: splitK=4, resid=x, atomic into zeroed x1
  hipMemsetAsync(x1, 0, TH * 4, stream);
  k_gemm_sk<<<dim3(HID / 128, T_SEQ / 128, 4), 256, 0, stream>>>(
      actbf, wout_bf, wout_bf, wout_bf, x1, x1, x1, x, T_SEQ, HID, HID, HID / 4, 4);
  k_rms<<<dim3(T_SEQ), 256, 0, stream>>>(x1, mnw, actbf);
  // fused gate/up + swiglu -> bf16
  k_gemm_gu<<<dim3(INTER / 128, T_SEQ / 128), 256, 0, stream>>>(actbf, wgate_bf, wup_bf, g_bf);
  // down projection: splitK=4, resid=x1, atomic into zeroed out
  hipMemsetAsync(out, 0, TH * 4, stream);
  k_gemm_sk<<<dim3(HID / 128, T_SEQ / 128, 4), 256, 0, stream>>>(
      g_bf, wdown_bf, wdown_bf, wdown_bf, out, out, out, x1, T_SEQ, HID, INTER, INTER / 4, 4);
}

// Round 4
// 659.380 us; speedup vs baseline: 1.4840x; 1.0712x over previous
//
#include <hip/hip_runtime.h>
#include <stdint.h>

typedef unsigned short u16;
typedef unsigned int u32;

#define T_SEQ 1024
#define HID   2048
#define NH    32
#define HD    64
#define NCHUNK 16
#define INTER 5632

typedef __attribute__((ext_vector_type(8))) short b16x8;
typedef __attribute__((ext_vector_type(4))) float f32x4;

__device__ inline float bf2f(u16 u) { union { u32 i; float f; } v; v.i = ((u32)u) << 16; return v.f; }
__device__ inline u16 f2bf(float f) {
  union { float f; u32 i; } v; v.f = f;
  u32 u = v.i;
  return (u16)((u + 0x7FFFu + ((u >> 16) & 1u)) >> 16);  // RNE
}
__device__ inline float silu_f(float x) { return x / (1.f + __expf(-x)); }

typedef __attribute__((address_space(1))) const unsigned int as1_u32;
typedef __attribute__((address_space(3))) unsigned int as3_u32;
__device__ inline void gl_lds16(const void* g, void* l) {
  __builtin_amdgcn_global_load_lds((as1_u32*)g, (as3_u32*)l, 16, 0, 0);
}

// ---------------- fp32 -> bf16 all-weights conversion (one launch) ----------------
__global__ __launch_bounds__(256) void k_cvt_all(
    const float* __restrict__ s0, const float* __restrict__ s1, const float* __restrict__ s2,
    const float* __restrict__ s3, const float* __restrict__ s4, const float* __restrict__ s5,
    const float* __restrict__ s6,
    u16* __restrict__ d0, u16* __restrict__ d1, u16* __restrict__ d2, u16* __restrict__ d3,
    u16* __restrict__ d4, u16* __restrict__ d5, u16* __restrict__ d6) {
  int z = blockIdx.y;
  int n4 = (z < 4) ? (HID * HID / 4) : (INTER * HID / 4);
  int i = blockIdx.x * 256 + threadIdx.x;
  if (i >= n4) return;
  const float* s = (z == 0) ? s0 : (z == 1) ? s1 : (z == 2) ? s2 : (z == 3) ? s3
                   : (z == 4) ? s4 : (z == 5) ? s5 : s6;
  u16* d = (z == 0) ? d0 : (z == 1) ? d1 : (z == 2) ? d2 : (z == 3) ? d3
           : (z == 4) ? d4 : (z == 5) ? d5 : d6;
  float4 v = ((const float4*)s)[i];
  u32 lo = (u32)f2bf(v.x) | ((u32)f2bf(v.y) << 16);
  u32 hi = (u32)f2bf(v.z) | ((u32)f2bf(v.w) << 16);
  ((uint2*)d)[i] = make_uint2(lo, hi);
}

// ---------------- RMSNorm: fp32 in -> bf16 out ----------------
__global__ __launch_bounds__(256) void k_rms(const float* __restrict__ x, const float* __restrict__ w,
                                             u16* __restrict__ out) {
  int row = blockIdx.x, tid = threadIdx.x;
  const float* xr = x + (size_t)row * HID;
  float4 v0 = ((const float4*)xr)[tid];
  float4 v1 = ((const float4*)xr)[tid + 256];
  float ss = v0.x * v0.x + v0.y * v0.y + v0.z * v0.z + v0.w * v0.w +
             v1.x * v1.x + v1.y * v1.y + v1.z * v1.z + v1.w * v1.w;
  for (int m = 32; m; m >>= 1) ss += __shfl_xor(ss, m, 64);
  __shared__ float wsum[4];
  if ((tid & 63) == 0) wsum[tid >> 6] = ss;
  __syncthreads();
  float tot = wsum[0] + wsum[1] + wsum[2] + wsum[3];
  float sc = rsqrtf(tot / (float)HID + 1e-6f);
  float4 w0 = ((const float4*)w)[tid];
  float4 w1 = ((const float4*)w)[tid + 256];
  u32 lo, hi;
  lo = (u32)f2bf(v0.x * sc * w0.x) | ((u32)f2bf(v0.y * sc * w0.y) << 16);
  hi = (u32)f2bf(v0.z * sc * w0.z) | ((u32)f2bf(v0.w * sc * w0.w) << 16);
  ((uint2*)out)[(size_t)row * 512 + tid] = make_uint2(lo, hi);
  lo = (u32)f2bf(v1.x * sc * w1.x) | ((u32)f2bf(v1.y * sc * w1.y) << 16);
  hi = (u32)f2bf(v1.z * sc * w1.z) | ((u32)f2bf(v1.w * sc * w1.w) << 16);
  ((uint2*)out)[(size_t)row * 512 + tid + 256] = make_uint2(lo, hi);
}

// ---------------- split-K bf16 GEMM, double-buffered LDS prefetch, atomicAdd fp32 epilogue ----
// C[M,N] += A[M,K] @ B[N,K]^T (slice) ; resid added by slice 0. C must be pre-zeroed.
__global__ __launch_bounds__(256) void k_gemm_sk(
    const u16* __restrict__ A,
    const u16* __restrict__ B0, const u16* __restrict__ B1, const u16* __restrict__ B2,
    float* __restrict__ C0, float* __restrict__ C1, float* __restrict__ C2,
    const float* __restrict__ resid, int M, int N, int Kf, int KS, int nslice) {
  int mat = blockIdx.z / nslice, slice = blockIdx.z % nslice;
  const u16* Bp = (mat == 0) ? B0 : (mat == 1 ? B1 : B2);
  float* Cp = (mat == 0) ? C0 : (mat == 1 ? C1 : C2);
  __shared__ __align__(16) u16 As[2][128 * 32];
  __shared__ __align__(16) u16 Bs[2][128 * 32];
  int tid = threadIdx.x;
  int m0 = blockIdx.y * 128, n0 = blockIdx.x * 128;
  int lane = tid & 63, wv = tid >> 6, wr = wv >> 1, wc = wv & 1;
  int lrow = lane & 15, quad = lane >> 4;
  int lr = lane >> 2;
  int lc = (((lane & 3) ^ ((lr >> 1) & 3)) * 8);  // XOR-swizzled source chunk
  int xq = quad ^ ((lrow >> 1) & 3);              // XOR-swizzled read chunk
  f32x4 acc[4][4];
#pragma unroll
  for (int i = 0; i < 4; ++i)
#pragma unroll
    for (int j = 0; j < 4; ++j) acc[i][j] = (f32x4){0.f, 0.f, 0.f, 0.f};

  const u16* Agb = A + (size_t)(m0 + wv * 32 + lr) * Kf + lc;
  const u16* Bgb = Bp + (size_t)(n0 + wv * 32 + lr) * Kf + lc;
  auto stage = [&](int k0, int b) {
    gl_lds16(Agb + k0,                     &As[b][(wv * 32) * 32]);
    gl_lds16(Agb + (size_t)16 * Kf + k0,   &As[b][(wv * 32 + 16) * 32]);
    gl_lds16(Bgb + k0,                     &Bs[b][(wv * 32) * 32]);
    gl_lds16(Bgb + (size_t)16 * Kf + k0,   &Bs[b][(wv * 32 + 16) * 32]);
  };
  int kb = slice * KS;
  int nIt = KS / 32;
  stage(kb, 0);
  __syncthreads();
  for (int it = 0; it < nIt; ++it) {
    int p = it & 1;
    if (it + 1 < nIt) stage(kb + (it + 1) * 32, p ^ 1);
    b16x8 af[4], bfr[4];
#pragma unroll
    for (int i = 0; i < 4; ++i) af[i] = *(const b16x8*)&As[p][(wr * 64 + i * 16 + lrow) * 32 + xq * 8];
#pragma unroll
    for (int j = 0; j < 4; ++j) bfr[j] = *(const b16x8*)&Bs[p][(wc * 64 + j * 16 + lrow) * 32 + xq * 8];
#pragma unroll
    for (int i = 0; i < 4; ++i)
#pragma unroll
      for (int j = 0; j < 4; ++j)
        acc[i][j] = __builtin_amdgcn_mfma_f32_16x16x32_bf16(af[i], bfr[j], acc[i][j], 0, 0, 0);
    __syncthreads();
  }
#pragma unroll
  for (int i = 0; i < 4; ++i)
#pragma unroll
    for (int j = 0; j < 4; ++j)
#pragma unroll
      for (int r = 0; r < 4; ++r) {
        int row = m0 + wr * 64 + i * 16 + quad * 4 + r;
        int col = n0 + wc * 64 + j * 16 + lrow;
        float val = acc[i][j][r];
        if (slice == 0 && resid) val += resid[(size_t)row * N + col];
        atomicAdd(&Cp[(size_t)row * N + col], val);
      }
}

// ---------------- fused gate/up GEMM + swiglu, dbuf + XCD-aware swizzle ----------------
// 1-D grid 384: xcd = flat%8, idx = flat/8; n = xcd + 8*(idx/8) (pad 48), m = idx%8.
__global__ __launch_bounds__(256) void k_gemm_gu(
    const u16* __restrict__ A, const u16* __restrict__ Bg, const u16* __restrict__ Bu,
    u16* __restrict__ D) {
  int flat = blockIdx.x;
  int xcd = flat & 7, idx = flat >> 3;
  int n = xcd + 8 * (idx >> 3), m = idx & 7;
  if (n >= INTER / 128) return;
  __shared__ __align__(16) u16 As[2][128 * 32];
  __shared__ __align__(16) u16 Gs[2][128 * 32];
  __shared__ __align__(16) u16 Us[2][128 * 32];
  int tid = threadIdx.x;
  int m0 = m * 128, n0 = n * 128;
  int lane = tid & 63, wv = tid >> 6, wr = wv >> 1, wc = wv & 1;
  int lrow = lane & 15, quad = lane >> 4;
  int lr = lane >> 2;
  int lc = (((lane & 3) ^ ((lr >> 1) & 3)) * 8);
  int xq = quad ^ ((lrow >> 1) & 3);
  f32x4 ag[4][4], au[4][4];
#pragma unroll
  for (int i = 0; i < 4; ++i)
#pragma unroll
    for (int j = 0; j < 4; ++j) { ag[i][j] = (f32x4){0.f, 0.f, 0.f, 0.f}; au[i][j] = (f32x4){0.f, 0.f, 0.f, 0.f}; }

  const u16* Agb = A + (size_t)(m0 + wv * 32 + lr) * HID + lc;
  const u16* Ggb = Bg + (size_t)(n0 + wv * 32 + lr) * HID + lc;
  const u16* Ugb = Bu + (size_t)(n0 + wv * 32 + lr) * HID + lc;
  auto stage = [&](int k0, int b) {
    gl_lds16(Agb + k0,                    &As[b][(wv * 32) * 32]);
    gl_lds16(Agb + (size_t)16 * HID + k0, &As[b][(wv * 32 + 16) * 32]);
    gl_lds16(Ggb + k0,                    &Gs[b][(wv * 32) * 32]);
    gl_lds16(Ggb + (size_t)16 * HID + k0, &Gs[b][(wv * 32 + 16) * 32]);
    gl_lds16(Ugb + k0,                    &Us[b][(wv * 32) * 32]);
    gl_lds16(Ugb + (size_t)16 * HID + k0, &Us[b][(wv * 32 + 16) * 32]);
  };
  stage(0, 0);
  __syncthreads();
  for (int it = 0; it < HID / 32; ++it) {
    int p = it & 1;
    if (it + 1 < HID / 32) stage((it + 1) * 32, p ^ 1);
    b16x8 af[4], gf[4], uf[4];
#pragma unroll
    for (int i = 0; i < 4; ++i) af[i] = *(const b16x8*)&As[p][(wr * 64 + i * 16 + lrow) * 32 + xq * 8];
#pragma unroll
    for (int j = 0; j < 4; ++j) gf[j] = *(const b16x8*)&Gs[p][(wc * 64 + j * 16 + lrow) * 32 + xq * 8];
#pragma unroll
    for (int j = 0; j < 4; ++j) uf[j] = *(const b16x8*)&Us[p][(wc * 64 + j * 16 + lrow) * 32 + xq * 8];
#pragma unroll
    for (int i = 0; i < 4; ++i)
#pragma unroll
      for (int j = 0; j < 4; ++j) {
        ag[i][j] = __builtin_amdgcn_mfma_f32_16x16x32_bf16(af[i], gf[j], ag[i][j], 0, 0, 0);
        au[i][j] = __builtin_amdgcn_mfma_f32_16x16x32_bf16(af[i], uf[j], au[i][j], 0, 0, 0);
      }
    __syncthreads();
  }
#pragma unroll
  for (int i = 0; i < 4; ++i)
#pragma unroll
    for (int j = 0; j < 4; ++j)
#pragma unroll
      for (int r = 0; r < 4; ++r) {
        int row = m0 + wr * 64 + i * 16 + quad * 4 + r;
        int col = n0 + wc * 64 + j * 16 + lrow;
        D[(size_t)row * INTER + col] = f2bf(silu_f(ag[i][j][r]) * au[i][j][r]);
      }
}

// ---------------- beta = sigmoid(h @ Wbeta^T) ----------------
__global__ __launch_bounds__(256) void k_beta(const u16* __restrict__ hbf, const float* __restrict__ Wb,
                                              float* __restrict__ beta) {
  __shared__ __align__(16) float hr[HID];
  __shared__ float red[256];
  int t = blockIdx.x, tid = threadIdx.x;
#pragma unroll
  for (int i = 0; i < 8; ++i) {
    int c = i * 256 + tid;
    hr[c] = bf2f(hbf[(size_t)t * HID + c]);
  }
  __syncthreads();
  int head = tid >> 3, j = tid & 7;
  const float* wrow = Wb + (size_t)head * HID + j * 256;
  const float* hs = hr + j * 256;
  float acc = 0.f;
#pragma unroll 16
  for (int c = 0; c < 256; c += 4) {
    float4 wv = *(const float4*)&wrow[c];
    float4 hv = *(const float4*)&hs[c];
    acc += hv.x * wv.x + hv.y * wv.y + hv.z * wv.z + hv.w * wv.w;
  }
  red[tid] = acc;
  __syncthreads();
  if (tid < 32) {
    float s = 0.f;
#pragma unroll
    for (int i = 0; i < 8; ++i) s += red[tid * 8 + i];
    beta[(size_t)t * NH + tid] = 1.f / (1.f + __expf(-s));
  }
}

// ---------------- causal depthwise conv (K=4) + silu(silu) (+ l2norm for q,k) ----------------
__global__ __launch_bounds__(256) void k_conv(const float* __restrict__ proj,
                                              const float* __restrict__ cw0, const float* __restrict__ cw1,
                                              const float* __restrict__ cw2, float* __restrict__ outp) {
  int z = blockIdx.z;
  const float* src = proj + (size_t)z * T_SEQ * HID;
  float* dst = outp + (size_t)z * T_SEQ * HID;
  const float* cw = (z == 0) ? cw0 : (z == 1 ? cw1 : cw2);
  bool l2 = (z < 2);
  int c = threadIdx.x & 63, wr = threadIdx.x >> 6;
  int head = blockIdx.y;
  int ch = head * 64 + c;
  int t0 = blockIdx.x * 64 + wr * 16;
  float4 w = ((const float4*)cw)[ch];
  float xm3 = (t0 >= 3) ? src[(size_t)(t0 - 3) * HID + ch] : 0.f;
  float xm2 = (t0 >= 2) ? src[(size_t)(t0 - 2) * HID + ch] : 0.f;
  float xm1 = (t0 >= 1) ? src[(size_t)(t0 - 1) * HID + ch] : 0.f;
  for (int i = 0; i < 16; ++i) {
    int t = t0 + i;
    float x0 = src[(size_t)t * HID + ch];
    float zv = xm3 * w.x + xm2 * w.y + xm1 * w.z + x0 * w.w;
    float s = silu_f(silu_f(zv));
    if (l2) {
      float ss = s * s;
      for (int m = 32; m; m >>= 1) ss += __shfl_xor(ss, m, 64);
      float n = sqrtf(ss);
      s = s / fmaxf(n, 1e-12f);
    }
    dst[(size_t)t * HID + ch] = s;
    xm3 = xm2; xm2 = xm1; xm1 = x0;
  }
}

// ---------------- Phase A ----------------
__global__ __launch_bounds__(256) void k_phaseA(
    const float* __restrict__ qp, const float* __restrict__ kp, const float* __restrict__ vp,
    const float* __restrict__ beta,
    u16* __restrict__ negWbf, u16* __restrict__ Uvbf, u16* __restrict__ Ktbf,
    u16* __restrict__ Qbf, u16* __restrict__ Pbf) {
  int cx = blockIdx.x, h = blockIdx.y;
  __shared__ __align__(16) u16 Kst[64 * 72];
  __shared__ __align__(16) u16 Qst[64 * 72];
  __shared__ __align__(16) float Af[64 * 68];
  __shared__ float bet[64];
  int tid = threadIdx.x;
  int t0 = cx * 64;
#pragma unroll
  for (int i = 0; i < 16; ++i) {
    int idx = i * 256 + tid, s = idx >> 6, d = idx & 63;
    size_t g = (size_t)(t0 + s) * HID + h * 64 + d;
    Kst[s * 72 + d] = f2bf(kp[g]);
    Qst[s * 72 + d] = f2bf(qp[g]);
  }
  if (tid < 64) bet[tid] = beta[(size_t)(t0 + tid) * NH + h];
  __syncthreads();
  int lane = tid & 63, wv = tid >> 6, lrow = lane & 15, quad = lane >> 4;
  f32x4 accA[4], accP[4];
#pragma unroll
  for (int i = 0; i < 4; ++i) { accA[i] = (f32x4){0.f, 0.f, 0.f, 0.f}; accP[i] = (f32x4){0.f, 0.f, 0.f, 0.f}; }
#pragma unroll
  for (int ks = 0; ks < 2; ++ks) {
    b16x8 bk = *(const b16x8*)&Kst[(wv * 16 + lrow) * 72 + ks * 32 + quad * 8];
#pragma unroll
    for (int i = 0; i < 4; ++i) {
      b16x8 ak = *(const b16x8*)&Kst[(i * 16 + lrow) * 72 + ks * 32 + quad * 8];
      b16x8 aq = *(const b16x8*)&Qst[(i * 16 + lrow) * 72 + ks * 32 + quad * 8];
      accA[i] = __builtin_amdgcn_mfma_f32_16x16x32_bf16(ak, bk, accA[i], 0, 0, 0);
      accP[i] = __builtin_amdgcn_mfma_f32_16x16x32_bf16(aq, bk, accP[i], 0, 0, 0);
    }
  }
  size_t cb2 = ((size_t)h * NCHUNK + cx) * 4096;
#pragma unroll
  for (int i = 0; i < 4; ++i)
#pragma unroll
    for (int r = 0; r < 4; ++r) {
      int srow = i * 16 + quad * 4 + r, col = wv * 16 + lrow;
      Af[srow * 68 + col] = (col < srow) ? accA[i][r] * bet[srow] : 0.f;
      Pbf[cb2 + srow * 64 + col] = f2bf((col <= srow) ? accP[i][r] : 0.f);
    }
  __syncthreads();
  if (wv < 2) {
    int c = lane;
    float x[64];
    if (wv == 0) {
#pragma unroll
      for (int s = 0; s < 64; ++s) x[s] = bet[s] * bf2f(Kst[s * 72 + c]);
    } else {
#pragma unroll
      for (int s = 0; s < 64; ++s) x[s] = bet[s] * vp[(size_t)(t0 + s) * HID + h * 64 + c];
    }
#pragma unroll
    for (int s = 1; s < 64; ++s) {
      float a = 0.f;
#pragma unroll
      for (int r = 0; r < (s & ~3); r += 4) {
        float4 av = *(const float4*)&Af[s * 68 + r];
        a += av.x * x[r] + av.y * x[r + 1] + av.z * x[r + 2] + av.w * x[r + 3];
      }
#pragma unroll
      for (int r = (s & ~3); r < s; ++r) a += Af[s * 68 + r] * x[r];
      x[s] -= a;
    }
    if (wv == 0) {
#pragma unroll
      for (int s = 0; s < 64; ++s) negWbf[cb2 + s * 64 + c] = f2bf(-x[s]);
    } else {
#pragma unroll
      for (int s = 0; s < 64; ++s) Uvbf[cb2 + s * 64 + c] = f2bf(x[s]);
    }
  } else if (wv == 2) {
#pragma unroll
    for (int it = 0; it < 8; ++it) {
      int cidx = it * 64 + lane, s = cidx >> 3, d0 = (cidx & 7) * 8;
      *(uint4*)&Qbf[cb2 + s * 64 + d0] = *(const uint4*)&Qst[s * 72 + d0];
    }
  } else {
#pragma unroll
    for (int it = 0; it < 8; ++it) {
      int cidx = it * 64 + lane, d = cidx >> 3, s0 = (cidx & 7) * 8;
      u16 tmp[8];
#pragma unroll
      for (int j = 0; j < 8; ++j) tmp[j] = Kst[(s0 + j) * 72 + d];
      *(uint4*)&Ktbf[cb2 + d * 64 + s0] = *(const uint4*)tmp;
    }
  }
}

// ---------------- Phase B1: serial per head ----------------
__global__ __launch_bounds__(256) void k_phaseB1(
    const u16* __restrict__ negWbf, const u16* __restrict__ Uvbf, const u16* __restrict__ Ktbf,
    u16* __restrict__ Utws, u16* __restrict__ Sws, float* __restrict__ Sout) {
  int h = blockIdx.x, tid = threadIdx.x;
  __shared__ __align__(16) u16 S0b[2][64 * 72];
  __shared__ __align__(16) u16 Ut[64 * 72];
  int lane = tid & 63, wv = tid >> 6, lrow = lane & 15, quad = lane >> 4;
#pragma unroll
  for (int i = 0; i < 16; ++i) {
    int idx = i * 256 + tid;
    S0b[0][(idx >> 6) * 72 + (idx & 63)] = 0;
  }
  f32x4 aS[4];
#pragma unroll
  for (int i = 0; i < 4; ++i) aS[i] = (f32x4){0.f, 0.f, 0.f, 0.f};

  b16x8 Wf[2][4][2]; b16x8 Ktf[2][2]; u16 Uvr[2][4][4];
  size_t hb = (size_t)h * NCHUNK * 4096;
  {
    size_t cb2 = hb;
#pragma unroll
    for (int i = 0; i < 4; ++i)
#pragma unroll
      for (int ks = 0; ks < 2; ++ks)
        Wf[0][i][ks] = *(const b16x8*)&negWbf[cb2 + (i * 16 + lrow) * 64 + ks * 32 + quad * 8];
#pragma unroll
    for (int ks = 0; ks < 2; ++ks)
      Ktf[0][ks] = *(const b16x8*)&Ktbf[cb2 + (wv * 16 + lrow) * 64 + ks * 32 + quad * 8];
#pragma unroll
    for (int i = 0; i < 4; ++i)
#pragma unroll
      for (int r = 0; r < 4; ++r)
        Uvr[0][i][r] = Uvbf[cb2 + (i * 16 + quad * 4 + r) * 64 + wv * 16 + lrow];
  }
  __syncthreads();
#pragma unroll
  for (int cx = 0; cx < NCHUNK; ++cx) {
    const int p = cx & 1, q = p ^ 1;
    size_t cb2 = hb + (size_t)cx * 4096;
    if (cx > 0) {
#pragma unroll
      for (int i = 0; i < 2; ++i) {
        int cidx = i * 256 + tid, dv = cidx >> 3, s0 = (cidx & 7) * 8;
        *(uint4*)&Sws[cb2 + dv * 64 + s0] = *(const uint4*)&S0b[p][dv * 72 + s0];
      }
    }
    if (cx + 1 < NCHUNK) {
      size_t cbn = cb2 + 4096;
#pragma unroll
      for (int i = 0; i < 4; ++i)
#pragma unroll
        for (int ks = 0; ks < 2; ++ks)
          Wf[q][i][ks] = *(const b16x8*)&negWbf[cbn + (i * 16 + lrow) * 64 + ks * 32 + quad * 8];
#pragma unroll
      for (int ks = 0; ks < 2; ++ks)
        Ktf[q][ks] = *(const b16x8*)&Ktbf[cbn + (wv * 16 + lrow) * 64 + ks * 32 + quad * 8];
#pragma unroll
      for (int i = 0; i < 4; ++i)
#pragma unroll
        for (int r = 0; r < 4; ++r)
          Uvr[q][i][r] = Uvbf[cbn + (i * 16 + quad * 4 + r) * 64 + wv * 16 + lrow];
    }
    f32x4 aU[4];
#pragma unroll
    for (int i = 0; i < 4; ++i)
#pragma unroll
      for (int r = 0; r < 4; ++r) aU[i][r] = bf2f(Uvr[p][i][r]);
#pragma unroll
    for (int ks = 0; ks < 2; ++ks) {
      b16x8 bS = *(const b16x8*)&S0b[p][(wv * 16 + lrow) * 72 + ks * 32 + quad * 8];
#pragma unroll
      for (int i = 0; i < 4; ++i)
        aU[i] = __builtin_amdgcn_mfma_f32_16x16x32_bf16(Wf[p][i][ks], bS, aU[i], 0, 0, 0);
    }
#pragma unroll
    for (int i = 0; i < 4; ++i)
#pragma unroll
      for (int r = 0; r < 4; ++r) {
        int s = i * 16 + quad * 4 + r, dv = wv * 16 + lrow;
        Ut[dv * 72 + s] = f2bf(aU[i][r]);
      }
    __syncthreads();
#pragma unroll
    for (int i = 0; i < 2; ++i) {
      int cidx = i * 256 + tid, dv = cidx >> 3, s0 = (cidx & 7) * 8;
      *(uint4*)&Utws[cb2 + dv * 64 + s0] = *(const uint4*)&Ut[dv * 72 + s0];
    }
#pragma unroll
    for (int ks = 0; ks < 2; ++ks) {
#pragma unroll
      for (int i = 0; i < 4; ++i) {
        b16x8 a = *(const b16x8*)&Ut[(i * 16 + lrow) * 72 + ks * 32 + quad * 8];
        aS[i] = __builtin_amdgcn_mfma_f32_16x16x32_bf16(a, Ktf[p][ks], aS[i], 0, 0, 0);
      }
    }
#pragma unroll
    for (int i = 0; i < 4; ++i)
#pragma unroll
      for (int r = 0; r < 4; ++r) {
        int dv = i * 16 + quad * 4 + r, dk = wv * 16 + lrow;
        S0b[q][dv * 72 + dk] = f2bf(aS[i][r]);
      }
    __syncthreads();
  }
#pragma unroll
  for (int i = 0; i < 4; ++i)
#pragma unroll
    for (int r = 0; r < 4; ++r) {
      int dv = i * 16 + quad * 4 + r, dk = wv * 16 + lrow;
      Sout[(size_t)h * 4096 + dv * 64 + dk] = aS[i][r];
    }
}

// ---------------- Phase B2: parallel O = Q S^T + P U ----------------
__global__ __launch_bounds__(256) void k_phaseB2(
    const u16* __restrict__ Qbf, const u16* __restrict__ Pbf,
    const u16* __restrict__ Utws, const u16* __restrict__ Sws, float* __restrict__ o) {
  int cx = blockIdx.x, h = blockIdx.y, tid = threadIdx.x;
  int lane = tid & 63, wv = tid >> 6, lrow = lane & 15, quad = lane >> 4;
  size_t cb2 = ((size_t)h * NCHUNK + cx) * 4096;
  f32x4 aO[4];
#pragma unroll
  for (int i = 0; i < 4; ++i) aO[i] = (f32x4){0.f, 0.f, 0.f, 0.f};
#pragma unroll
  for (int ks = 0; ks < 2; ++ks) {
    b16x8 Uf = *(const b16x8*)&Utws[cb2 + (wv * 16 + lrow) * 64 + ks * 32 + quad * 8];
#pragma unroll
    for (int i = 0; i < 4; ++i) {
      b16x8 Pf = *(const b16x8*)&Pbf[cb2 + (i * 16 + lrow) * 64 + ks * 32 + quad * 8];
      aO[i] = __builtin_amdgcn_mfma_f32_16x16x32_bf16(Pf, Uf, aO[i], 0, 0, 0);
    }
  }
  if (cx > 0) {
#pragma unroll
    for (int ks = 0; ks < 2; ++ks) {
      b16x8 Sf = *(const b16x8*)&Sws[cb2 + (wv * 16 + lrow) * 64 + ks * 32 + quad * 8];
#pragma unroll
      for (int i = 0; i < 4; ++i) {
        b16x8 Qf = *(const b16x8*)&Qbf[cb2 + (i * 16 + lrow) * 64 + ks * 32 + quad * 8];
        aO[i] = __builtin_amdgcn_mfma_f32_16x16x32_bf16(Qf, Sf, aO[i], 0, 0, 0);
      }
    }
  }
  int t0 = cx * 64;
#pragma unroll
  for (int i = 0; i < 4; ++i)
#pragma unroll
    for (int r = 0; r < 4; ++r)
      o[(size_t)(t0 + i * 16 + quad * 4 + r) * HID + h * 64 + wv * 16 + lrow] = aO[i][r];
}

extern "C" void kernel_launch(void* const* d_in, const int* in_sizes, int n_in,
                              void* d_out, int out_size, void* d_ws, size_t ws_size,
                              hipStream_t stream) {
  const float* x     = (const float*)d_in[0];
  const float* anw   = (const float*)d_in[1];
  const float* Wq    = (const float*)d_in[2];
  const float* Wk    = (const float*)d_in[3];
  const float* Wv    = (const float*)d_in[4];
  const float* convq = (const float*)d_in[5];
  const float* convk = (const float*)d_in[6];
  const float* convv = (const float*)d_in[7];
  const float* Wbeta = (const float*)d_in[8];
  const float* onw   = (const float*)d_in[9];
  const float* Wout  = (const float*)d_in[10];
  const float* mnw   = (const float*)d_in[11];
  const float* Wgate = (const float*)d_in[12];
  const float* Wup   = (const float*)d_in[13];
  const float* Wdown = (const float*)d_in[14];
  float* out = (float*)d_out;

  const size_t TH = (size_t)T_SEQ * HID;
  const size_t SCAN = (size_t)NH * NCHUNK * 4096;
  char* wsb = (char*)d_ws;
  size_t off = 0;
  auto alloc = [&](size_t bytes) -> void* {
    void* p = wsb + off;
    off += (bytes + 255) & ~(size_t)255;
    return p;
  };
  u16* wq_bf    = (u16*)alloc((size_t)HID * HID * 2);
  u16* wk_bf    = (u16*)alloc((size_t)HID * HID * 2);
  u16* wv_bf    = (u16*)alloc((size_t)HID * HID * 2);
  u16* wout_bf  = (u16*)alloc((size_t)HID * HID * 2);
  u16* wgate_bf = (u16*)alloc((size_t)INTER * HID * 2);
  u16* wup_bf   = (u16*)alloc((size_t)INTER * HID * 2);
  u16* wdown_bf = (u16*)alloc((size_t)HID * INTER * 2);
  u16* actbf    = (u16*)alloc(TH * 2);
  float* qkv_proj = (float*)alloc(3 * TH * 4);   // aliased later: obuf
  float* qkvpost  = (float*)alloc(3 * TH * 4);
  float* betab    = (float*)alloc((size_t)T_SEQ * NH * 4);
  u16* negWbf = (u16*)alloc(SCAN * 2);           // aliased later by g_bf
  u16* Uvbf   = (u16*)alloc(SCAN * 2);
  u16* Ktbf   = (u16*)alloc(SCAN * 2);
  u16* Qbf    = (u16*)alloc(SCAN * 2);
  u16* Pbf    = (u16*)alloc(SCAN * 2);
  u16* Utws   = (u16*)alloc(SCAN * 2);
  u16* Sws    = (u16*)alloc(SCAN * 2);
  float* x1   = (float*)alloc(TH * 4);
  float* obuf = qkv_proj;   // qkv_proj dead after conv
  u16* g_bf   = negWbf;     // scan buffers dead after B2 (11.5MB < 3x4.19MB)

  // ---- zero all atomic targets up front (no later serialization) ----
  hipMemsetAsync(qkv_proj, 0, 3 * TH * 4, stream);
  hipMemsetAsync(x1, 0, TH * 4, stream);
  hipMemsetAsync(out, 0, TH * 4, stream);

  // ---- all weight conversions in one launch ----
  k_cvt_all<<<dim3(INTER * HID / 4 / 256, 7), 256, 0, stream>>>(
      Wq, Wk, Wv, Wout, Wgate, Wup, Wdown,
      wq_bf, wk_bf, wv_bf, wout_bf, wgate_bf, wup_bf, wdown_bf);

  k_rms<<<dim3(T_SEQ), 256, 0, stream>>>(x, anw, actbf);
  // qkv projections: splitK=2 (768 blocks = 3/CU), atomic into zeroed qkv_proj
  k_gemm_sk<<<dim3(HID / 128, T_SEQ / 128, 6), 256, 0, stream>>>(
      actbf, wq_bf, wk_bf, wv_bf, qkv_proj, qkv_proj + TH, qkv_proj + 2 * TH, nullptr,
      T_SEQ, HID, HID, HID / 2, 2);
  k_beta<<<dim3(T_SEQ), 256, 0, stream>>>(actbf, Wbeta, betab);
  k_conv<<<dim3(T_SEQ / 64, NH, 3), 256, 0, stream>>>(qkv_proj, convq, convk, convv, qkvpost);
  k_phaseA<<<dim3(NCHUNK, NH), 256, 0, stream>>>(
      qkvpost, qkvpost + TH, qkvpost + 2 * TH, betab, negWbf, Uvbf, Ktbf, Qbf, Pbf);
  k_phaseB1<<<dim3(NH), 256, 0, stream>>>(negWbf, Uvbf, Ktbf, Utws, Sws, out + TH);
  k_phaseB2<<<dim3(NCHUNK, NH), 256, 0, stream>>>(Qbf, Pbf, Utws, Sws, obuf);
  k_rms<<<dim3(T_SEQ), 256, 0, stream>>>(obuf, onw, actbf);
  // out projection: splitK=4 (512 blocks = 2/CU), resid=x, atomic into zeroed x1
  k_gemm_sk<<<dim3(HID / 128, T_SEQ / 128, 4), 256, 0, stream>>>(
      actbf, wout_bf, wout_bf, wout_bf, x1, x1, x1, x, T_SEQ, HID, HID, HID / 4, 4);
  k_rms<<<dim3(T_SEQ), 256, 0, stream>>>(x1, mnw, actbf);
  // fused gate/up + swiglu -> bf16 (384-block XCD-swizzled grid)
  k_gemm_gu<<<dim3(384), 256, 0, stream>>>(actbf, wgate_bf, wup_bf, g_bf);
  // down projection: splitK=4 (512 blocks = 2/CU), resid=x1, atomic into zeroed out
  k_gemm_sk<<<dim3(HID / 128, T_SEQ / 128, 4), 256, 0, stream>>>(
      g_bf, wdown_bf, wdown_bf, wdown_bf, out, out, out, x1, T_SEQ, HID, INTER, INTER / 4, 4);
}